// Round 9
// baseline (966.078 us; speedup 1.0000x reference)
//
#include <hip/hip_runtime.h>

// ---------------------------------------------------------------------------
// DualGNN: 2x (3-layer GCN encoder + mean-pool) + MLP head. All f32.
// NUMERICS POLICY (hard-won, R5-R8): within-row summation order must track
// the reference edge order. Keep SB=32; keep fillrank's round-sequential
// loop (NO unroll); keep agg verbatim from the round-4-passing kernel (NO
// deeper FP unroll — reassociation risk). Only provably order-neutral
// optimizations allowed: hist unroll (integer counts), chunk-axis
// parallelism (partition by dst VALUE — order-neutral, R8-validated),
// reg-batched reduce, integer-only pool counting.
// R9 change vs R8: CHUNK 6400 -> 1600 (NCH 8 -> 32). Code byte-identical.
// fillrank was 1 wave/SIMD (occupancy 9.7%) -> latency-bound; this gives
// 4 blocks/CU (16 waves/CU) for the same per-block rank semantics.
// ---------------------------------------------------------------------------

#define DHID 128
#define CHUNK 1600    // nodes per chunk (LDS histo: 6.4 KB) — order-neutral
#define SB 32         // edge slices — DO NOT CHANGE (numerics)

static __device__ __forceinline__ void fma4(float4& o, float a, const float4& w) {
  o.x = fmaf(a, w.x, o.x);
  o.y = fmaf(a, w.y, o.y);
  o.z = fmaf(a, w.z, o.z);
  o.w = fmaf(a, w.w, o.w);
}
static __device__ __forceinline__ void add4(float4& o, const float4& v) {
  o.x += v.x; o.y += v.y; o.z += v.z; o.w += v.w;
}

// ---- pass 1: privatized histograms -> u16 partials (4x unrolled) ----------
// Pure counting: order-free, unroll provably exact.
__global__ __launch_bounds__(256) void hist_kernel(
    const int* __restrict__ src, const int* __restrict__ dst,
    unsigned short* __restrict__ parts, int E, int es) {
  __shared__ unsigned int h[CHUNK + 1];   // +1 dummy bin for out-of-chunk
  const int t = threadIdx.x;
  const int slice = blockIdx.x;
  const int chunk = blockIdx.y;
  const int arr = blockIdx.z;
  for (int i = t; i <= CHUNK; i += 256) h[i] = 0;
  __syncthreads();
  const int* __restrict__ idx = arr ? dst : src;
  const int base = chunk * CHUNK;
  const int e0 = slice * es;
  const int e1 = min(e0 + es, E);
  int e = e0 + t;
  for (; e + 768 < e1; e += 1024) {
    int i0 = idx[e], i1 = idx[e + 256], i2 = idx[e + 512], i3 = idx[e + 768];
    unsigned c0 = min((unsigned)(i0 - base), (unsigned)CHUNK);
    unsigned c1 = min((unsigned)(i1 - base), (unsigned)CHUNK);
    unsigned c2 = min((unsigned)(i2 - base), (unsigned)CHUNK);
    unsigned c3 = min((unsigned)(i3 - base), (unsigned)CHUNK);
    atomicAdd(&h[c0], 1u);
    atomicAdd(&h[c1], 1u);
    atomicAdd(&h[c2], 1u);
    atomicAdd(&h[c3], 1u);
  }
  for (; e < e1; e += 256) {
    unsigned c = min((unsigned)(idx[e] - base), (unsigned)CHUNK);
    atomicAdd(&h[c], 1u);
  }
  __syncthreads();
  unsigned short* p = parts + (((size_t)arr * gridDim.y + chunk) * SB + slice) * CHUNK;
  for (int i = t; i < CHUNK; i += 256) p[i] = (unsigned short)h[i];
}

// ---- pass 2: register-batched reduce of partials (no atomics) -------------
__global__ __launch_bounds__(256) void reduce_kernel(
    unsigned short* __restrict__ parts,
    int* __restrict__ deg_in, float* __restrict__ nsrc, float* __restrict__ ndst,
    int* __restrict__ sp, int N, int nch) {
  const int t = threadIdx.x;
  const int n = blockIdx.x * 256 + t;
  int sumD = 0;
  if (n < N) {
    const int chunk = n / CHUNK;
    const int local = n % CHUNK;
    const size_t strideA = (size_t)nch * SB * CHUNK;
    const unsigned short* __restrict__ pS = parts + ((size_t)chunk * SB) * CHUNK + local;
    unsigned short* __restrict__ pD = parts + strideA + ((size_t)chunk * SB) * CHUNK + local;
    int sumS = 0;
    #pragma unroll
    for (int s = 0; s < SB; ++s) sumS += (int)pS[(size_t)s * CHUNK];
    unsigned short vD[SB];
    #pragma unroll
    for (int s = 0; s < SB; ++s) vD[s] = pD[(size_t)s * CHUNK];
    #pragma unroll
    for (int s = 0; s < SB; ++s) {
      int c = (int)vD[s];
      vD[s] = (unsigned short)sumD;   // per-slice exclusive offset
      sumD += c;
    }
    #pragma unroll
    for (int s = 0; s < SB; ++s) pD[(size_t)s * CHUNK] = vD[s];
    deg_in[n] = sumD;
    nsrc[n] = 1.0f / sqrtf((float)max(sumS, 1));
    ndst[n] = 1.0f / sqrtf((float)max(sumD, 1));
  }
  int v = sumD;
  #pragma unroll
  for (int d = 32; d > 0; d >>= 1) v += __shfl_xor(v, d);
  __shared__ int ws[4];
  if ((t & 63) == 0) ws[t >> 6] = v;
  __syncthreads();
  if (t == 0) sp[blockIdx.x] = ws[0] + ws[1] + ws[2] + ws[3];
}

// ---- scan of block sums (single block, nb<=256) ---------------------------
__global__ void scan_mid(int* __restrict__ part, int* __restrict__ total_out, int nb) {
  const int tid = threadIdx.x;
  const int lane = tid & 63;
  const int wv = tid >> 6;
  int v = (tid < nb) ? part[tid] : 0;
  int x = v;
  #pragma unroll
  for (int d = 1; d < 64; d <<= 1) {
    int y = __shfl_up(x, d);
    if (lane >= d) x += y;
  }
  __shared__ int ws[4];
  if (lane == 63) ws[wv] = x;
  __syncthreads();
  int woff = 0;
  for (int k = 0; k < wv; ++k) woff += ws[k];
  if (tid < nb) part[tid] = woff + x - v;
  if (tid == 255) *total_out = woff + x;
}

// ---- block-local exclusive scan + block offset -> rowptr ------------------
__global__ void scan_final(const int* __restrict__ deg, const int* __restrict__ part,
                           int* __restrict__ rowptr, int n) {
  const int tid = threadIdx.x;
  const int i = blockIdx.x * 256 + tid;
  const int lane = tid & 63;
  const int wv = tid >> 6;
  int v = (i < n) ? deg[i] : 0;
  int x = v;
  #pragma unroll
  for (int d = 1; d < 64; d <<= 1) {
    int y = __shfl_up(x, d);
    if (lane >= d) x += y;
  }
  __shared__ int ws[4];
  if (lane == 63) ws[wv] = x;
  __syncthreads();
  int woff = 0;
  for (int k = 0; k < wv; ++k) woff += ws[k];
  if (i < n) rowptr[i] = part[blockIdx.x] + woff + x - v;
}

// ---- pass 3: LDS rank + scatter -> colidx ----------------------------------
// VERBATIM round-4 inner loop (round-sequential: within-row order tracks
// edge order). DO NOT UNROLL (numerics).
__global__ __launch_bounds__(256) void fillrank_kernel(
    const int* __restrict__ src, const int* __restrict__ dst,
    const unsigned short* __restrict__ partD, const int* __restrict__ rowptr,
    int* __restrict__ colidx, int E, int es) {
  __shared__ unsigned int h[CHUNK];
  const int t = threadIdx.x;
  const int slice = blockIdx.x;
  const int chunk = blockIdx.y;
  for (int i = t; i < CHUNK; i += 256) h[i] = 0;
  __syncthreads();
  const int base = chunk * CHUNK;
  const unsigned short* __restrict__ po = partD + ((size_t)chunk * SB + slice) * CHUNK;
  const int e0 = slice * es;
  const int e1 = min(e0 + es, E);
  for (int e = e0 + t; e < e1; e += 256) {
    int d = dst[e];
    unsigned v = (unsigned)(d - base);
    if (v < CHUNK) {
      int rank = (int)atomicAdd(&h[v], 1u);
      int slot = rowptr[d] + (int)po[v] + rank;
      colidx[slot] = src[e];
    }
  }
}

// ---- tiled GEMM: out[n][c] = sum_k (nsrc[n]*A[n][k])*W[k][c], C=128 -------
#define BM 128
#define BKC 32
__global__ __launch_bounds__(256) void gemm_scaled(
    const float* __restrict__ A, const float* __restrict__ W,
    const float* __restrict__ nsrc, float* __restrict__ out,
    int nrows, int K) {
  __shared__ __align__(16) float As[BM][BKC + 4];
  __shared__ __align__(16) float Ws[BKC][DHID];
  const int tid = threadIdx.x;
  const int row0 = blockIdx.x * BM;
  const int cx = tid & 15;
  const int ry = tid >> 4;
  const int lr = tid >> 1;
  const int lk = (tid & 1) * 16;
  const int wk = tid >> 3;
  const int wc = (tid & 7) * 4;

  float4 acc[8][2];
  #pragma unroll
  for (int r = 0; r < 8; ++r) {
    acc[r][0] = make_float4(0.f, 0.f, 0.f, 0.f);
    acc[r][1] = make_float4(0.f, 0.f, 0.f, 0.f);
  }

  const int arow = row0 + lr;
  const float scale = (arow < nrows) ? nsrc[arow] : 0.f;

  for (int k0 = 0; k0 < K; k0 += BKC) {
    if (arow < nrows) {
      const float4* ap = (const float4*)(A + (size_t)arow * K + k0 + lk);
      #pragma unroll
      for (int j = 0; j < 4; ++j) {
        float4 v = ap[j];
        v.x *= scale; v.y *= scale; v.z *= scale; v.w *= scale;
        *(float4*)&As[lr][lk + j * 4] = v;
      }
    } else {
      #pragma unroll
      for (int j = 0; j < 4; ++j)
        *(float4*)&As[lr][lk + j * 4] = make_float4(0.f, 0.f, 0.f, 0.f);
    }
    {
      const float* wp = W + (size_t)(k0 + wk) * DHID;
      #pragma unroll
      for (int j = 0; j < 4; ++j)
        *(float4*)&Ws[wk][wc + j * 32] = *(const float4*)(wp + wc + j * 32);
    }
    __syncthreads();
    #pragma unroll 4
    for (int kk = 0; kk < BKC; kk += 2) {
      float4 w00 = *(float4*)&Ws[kk][cx * 4];
      float4 w01 = *(float4*)&Ws[kk][64 + cx * 4];
      float4 w10 = *(float4*)&Ws[kk + 1][cx * 4];
      float4 w11 = *(float4*)&Ws[kk + 1][64 + cx * 4];
      #pragma unroll
      for (int r = 0; r < 8; ++r) {
        float2 a = *(float2*)&As[ry + 16 * r][kk];
        fma4(acc[r][0], a.x, w00);
        fma4(acc[r][1], a.x, w01);
        fma4(acc[r][0], a.y, w10);
        fma4(acc[r][1], a.y, w11);
      }
    }
    __syncthreads();
  }
  #pragma unroll
  for (int r = 0; r < 8; ++r) {
    int row = row0 + ry + 16 * r;
    if (row < nrows) {
      float* op = out + (size_t)row * DHID;
      *(float4*)(op + cx * 4) = acc[r][0];
      *(float4*)(op + 64 + cx * 4) = acc[r][1];
    }
  }
}

// ---- aggregation: VERBATIM round-4-passing version ------------------------
__global__ void agg_kernel(const float* __restrict__ hB, const int* __restrict__ rowptr,
                           const int* __restrict__ colidx, const float* __restrict__ ndst,
                           const float* __restrict__ bias, float* __restrict__ out, int N) {
  int wid = (blockIdx.x * blockDim.x + threadIdx.x) >> 6;
  int lane = threadIdx.x & 63;
  if (wid >= N) return;
  int beg = rowptr[wid];
  int end = rowptr[wid + 1];
  const int half = lane >> 5;
  const int col = (lane & 31) * 4;
  float4 acc = make_float4(0.f, 0.f, 0.f, 0.f);

  for (int c0 = beg; c0 < end; c0 += 64) {
    int cnt = min(end - c0, 64);
    int myidx = (lane < cnt) ? colidx[c0 + lane] : 0;
    int pairs = cnt >> 1;
    int j = 0;
    for (; j + 4 <= pairs; j += 4) {
      int s0 = __shfl(myidx, 2 * j + half);
      int s1 = __shfl(myidx, 2 * j + 2 + half);
      int s2 = __shfl(myidx, 2 * j + 4 + half);
      int s3 = __shfl(myidx, 2 * j + 6 + half);
      float4 v0 = *(const float4*)(hB + (size_t)s0 * DHID + col);
      float4 v1 = *(const float4*)(hB + (size_t)s1 * DHID + col);
      float4 v2 = *(const float4*)(hB + (size_t)s2 * DHID + col);
      float4 v3 = *(const float4*)(hB + (size_t)s3 * DHID + col);
      add4(acc, v0); add4(acc, v1); add4(acc, v2); add4(acc, v3);
    }
    for (; j < pairs; ++j) {
      int s = __shfl(myidx, 2 * j + half);
      float4 v = *(const float4*)(hB + (size_t)s * DHID + col);
      add4(acc, v);
    }
    if (cnt & 1) {
      int s = __shfl(myidx, cnt - 1);
      if (half == 0) {
        float4 v = *(const float4*)(hB + (size_t)s * DHID + col);
        add4(acc, v);
      }
    }
  }
  acc.x += __shfl_xor(acc.x, 32);
  acc.y += __shfl_xor(acc.y, 32);
  acc.z += __shfl_xor(acc.z, 32);
  acc.w += __shfl_xor(acc.w, 32);
  if (half == 0) {
    float nd = ndst[wid];
    float4 b = *(const float4*)(bias + col);
    float4 o;
    o.x = fmaxf(fmaf(acc.x, nd, b.x), 0.f);
    o.y = fmaxf(fmaf(acc.y, nd, b.y), 0.f);
    o.z = fmaxf(fmaf(acc.z, nd, b.z), 0.f);
    o.w = fmaxf(fmaf(acc.w, nd, b.w), 0.f);
    *(float4*)(out + (size_t)wid * DHID + col) = o;
  }
}

// ---- mean-pool: run-flush over sorted gid, fused per-graph counting -------
__global__ void pool_kernel(const float* __restrict__ h, const int* __restrict__ gid,
                            float* __restrict__ pooled, int* __restrict__ cnt,
                            int N, int C) {
  int wid = (blockIdx.x * blockDim.x + threadIdx.x) >> 6;
  int lane = threadIdx.x & 63;
  int n0 = wid * C;
  if (n0 >= N) return;
  int n1 = min(n0 + C, N);
  int gcur = gid[n0];
  int runcnt = 0;
  float2 acc = make_float2(0.f, 0.f);
  for (int nd = n0; nd < n1; ++nd) {
    int g = gid[nd];
    if (g != gcur) {
      atomicAdd(&pooled[(size_t)gcur * DHID + lane * 2], acc.x);
      atomicAdd(&pooled[(size_t)gcur * DHID + lane * 2 + 1], acc.y);
      if (lane == 0) atomicAdd(&cnt[gcur], runcnt);
      acc = make_float2(0.f, 0.f);
      runcnt = 0;
      gcur = g;
    }
    const float2 v = *(const float2*)(h + (size_t)nd * DHID + lane * 2);
    acc.x += v.x;
    acc.y += v.y;
    ++runcnt;
  }
  atomicAdd(&pooled[(size_t)gcur * DHID + lane * 2], acc.x);
  atomicAdd(&pooled[(size_t)gcur * DHID + lane * 2 + 1], acc.y);
  if (lane == 0) atomicAdd(&cnt[gcur], runcnt);
}

// ---- MLP head: one block (128 thr) per graph ------------------------------
__global__ void mlp_kernel(const float* __restrict__ psu, const float* __restrict__ psv,
                           const int* __restrict__ cnt_su, const int* __restrict__ cnt_sv,
                           const float* __restrict__ gf,
                           const float* __restrict__ W0, const float* __restrict__ b0,
                           const float* __restrict__ W1, const float* __restrict__ b1,
                           const float* __restrict__ W2, const float* __restrict__ b2,
                           float* __restrict__ out) {
  int g = blockIdx.x;
  int t = threadIdx.x;  // 128 threads
  __shared__ float comb[260];
  __shared__ float h0[128];
  __shared__ float h1[64];
  float inv_su = 1.0f / (float)max(cnt_su[g], 1);
  float inv_sv = 1.0f / (float)max(cnt_sv[g], 1);
  comb[t] = psu[(size_t)g * DHID + t] * inv_su;
  comb[128 + t] = psv[(size_t)g * DHID + t] * inv_sv;
  if (t < 4) comb[256 + t] = gf[g * 4 + t];
  __syncthreads();
  float acc = b0[t];
  for (int k = 0; k < 260; ++k) acc = fmaf(comb[k], W0[k * 128 + t], acc);
  h0[t] = fmaxf(acc, 0.f);
  __syncthreads();
  if (t < 64) {
    float a = b1[t];
    for (int k = 0; k < 128; ++k) a = fmaf(h0[k], W1[k * 64 + t], a);
    h1[t] = fmaxf(a, 0.f);
  }
  __syncthreads();
  if (t < 64) {
    float p = h1[t] * W2[t];
    #pragma unroll
    for (int d = 32; d > 0; d >>= 1) p += __shfl_down(p, d);
    if (t == 0) out[g] = p + b2[0];
  }
}

// ---------------------------------------------------------------------------
extern "C" void kernel_launch(void* const* d_in, const int* in_sizes, int n_in,
                              void* d_out, int out_size, void* d_ws, size_t ws_size,
                              hipStream_t stream) {
  const float* solute_x  = (const float*)d_in[0];
  const float* solvent_x = (const float*)d_in[1];
  const float* gfeat     = (const float*)d_in[2];
  const int* su_src = (const int*)d_in[3];
  const int* su_dst = (const int*)d_in[4];
  const int* sv_src = (const int*)d_in[5];
  const int* sv_dst = (const int*)d_in[6];
  const int* su_gid = (const int*)d_in[7];
  const int* sv_gid = (const int*)d_in[8];
  const float* enc_W[2][3] = {
    {(const float*)d_in[9],  (const float*)d_in[10], (const float*)d_in[11]},
    {(const float*)d_in[13], (const float*)d_in[14], (const float*)d_in[15]}};
  const float* enc_b[2] = {(const float*)d_in[12], (const float*)d_in[16]};
  const float* mW0 = (const float*)d_in[17];
  const float* mb0 = (const float*)d_in[18];
  const float* mW1 = (const float*)d_in[19];
  const float* mb1 = (const float*)d_in[20];
  const float* mW2 = (const float*)d_in[21];
  const float* mb2 = (const float*)d_in[22];

  const int N = in_sizes[0] / 64;   // 50000
  const int E = in_sizes[3];        // 800000
  const int G = in_sizes[2] / 4;    // 256

  const int* srcs[2] = {su_src, sv_src};
  const int* dsts[2] = {su_dst, sv_dst};
  const int* gids[2] = {su_gid, sv_gid};
  const float* xs[2] = {solute_x, solvent_x};

  // workspace carve-up (256B aligned)
  char* ws = (char*)d_ws;
  size_t off = 0;
  auto alloc = [&](size_t bytes) -> void* {
    void* p = ws + off;
    off = (off + bytes + 255) & ~(size_t)255;
    return p;
  };
  const int NB = (N + 255) / 256;            // rowptr scan blocks (196)
  const int NCH = (N + CHUNK - 1) / CHUNK;   // chunks (32)
  const int RB = (NCH * CHUNK + 255) / 256;  // reduce blocks (200)
  const int ES = (E + SB - 1) / SB;          // edges per slice (25000)
  const size_t arrStride = (size_t)NCH * SB * CHUNK;  // u16 elems per array

  int*   deg_in  = (int*)alloc((size_t)N * 4);
  float* nsrc    = (float*)alloc((size_t)N * 4);
  float* ndst    = (float*)alloc((size_t)N * 4);
  int*   rowptr  = (int*)alloc((size_t)(N + 1) * 4);
  int*   sp      = (int*)alloc((size_t)RB * 4);
  unsigned short* parts = (unsigned short*)alloc(2 * arrStride * 2);
  int*   colidx  = (int*)alloc((size_t)E * 4);
  float* bufA    = (float*)alloc((size_t)N * DHID * 4);
  float* bufB    = (float*)alloc((size_t)N * DHID * 4);
  float* pbase   = (float*)alloc(((size_t)2 * G * DHID + 2 * G) * 4);
  float* pooled_su = pbase;
  float* pooled_sv = pbase + (size_t)G * DHID;
  int*   cnt_su    = (int*)(pbase + (size_t)2 * G * DHID);
  int*   cnt_sv    = cnt_su + G;
  (void)ws_size; (void)n_in; (void)out_size;

  float* pooleds[2] = {pooled_su, pooled_sv};
  int*   cnts[2]    = {cnt_su, cnt_sv};

  hipMemsetAsync(pbase, 0, ((size_t)2 * G * DHID + 2 * G) * 4, stream);

  const int TB = 256;
  const int ggrid = (N + BM - 1) / BM;
  const int agrid = (N + 3) / 4;               // wave per node
  const int PC = 25;                           // nodes per wave in pool
  const int pwaves = (N + PC - 1) / PC;
  const int pgrid = (pwaves + 3) / 4;

  for (int enc = 0; enc < 2; ++enc) {
    hist_kernel<<<dim3(SB, NCH, 2), TB, 0, stream>>>(srcs[enc], dsts[enc], parts, E, ES);
    reduce_kernel<<<RB, TB, 0, stream>>>(parts, deg_in, nsrc, ndst, sp, N, NCH);
    scan_mid<<<1, 256, 0, stream>>>(sp, rowptr + N, NB);
    scan_final<<<NB, 256, 0, stream>>>(deg_in, sp, rowptr, N);
    fillrank_kernel<<<dim3(SB, NCH), TB, 0, stream>>>(srcs[enc], dsts[enc],
                                                      parts + arrStride, rowptr,
                                                      colidx, E, ES);

    const float* in = xs[enc];
    int K = 64;
    for (int l = 0; l < 3; ++l) {
      gemm_scaled<<<ggrid, TB, 0, stream>>>(in, enc_W[enc][l], nsrc, bufB, N, K);
      agg_kernel<<<agrid, TB, 0, stream>>>(bufB, rowptr, colidx, ndst,
                                           enc_b[enc] + l * DHID, bufA, N);
      in = bufA;
      K = DHID;
    }
    pool_kernel<<<pgrid, TB, 0, stream>>>(bufA, gids[enc], pooleds[enc], cnts[enc], N, PC);
  }

  mlp_kernel<<<G, 128, 0, stream>>>(pooled_su, pooled_sv, cnt_su, cnt_sv, gfeat,
                                    mW0, mb0, mW1, mb1, mW2, mb2, (float*)d_out);
}

// Round 10
// 666.201 us; speedup vs baseline: 1.4501x; 1.4501x over previous
//
#include <hip/hip_runtime.h>

// ---------------------------------------------------------------------------
// DualGNN: 2x (3-layer GCN encoder + mean-pool) + MLP head. All f32.
// NUMERICS POLICY (hard-won, R5-R8): within-row summation order must track
// the reference edge order. Keep SB=32; keep fillrank's round-sequential
// loop (NO unroll); keep agg verbatim from the round-4-passing kernel.
// Order-neutral opts only: hist unroll (integer counts), chunk-axis
// parallelism (partition by dst VALUE), reg-batched reduce, int pool counts.
// R10 change vs R9: hist uses predicated `if (v<CHUNK)` atomics again —
// R9's min()-dummy-bin sent 97% of lanes to ONE LDS address (4.8e7 bank
// conflicts, 62-way atomic serialization). Guarded lanes issue no LDS op.
// ---------------------------------------------------------------------------

#define DHID 128
#define CHUNK 1600    // nodes per chunk (LDS histo: 6.4 KB) — order-neutral
#define SB 32         // edge slices — DO NOT CHANGE (numerics)

static __device__ __forceinline__ void fma4(float4& o, float a, const float4& w) {
  o.x = fmaf(a, w.x, o.x);
  o.y = fmaf(a, w.y, o.y);
  o.z = fmaf(a, w.z, o.z);
  o.w = fmaf(a, w.w, o.w);
}
static __device__ __forceinline__ void add4(float4& o, const float4& v) {
  o.x += v.x; o.y += v.y; o.z += v.z; o.w += v.w;
}

// ---- pass 1: privatized histograms -> u16 partials (4x load-batched) ------
// Pure counting: order-free. Out-of-chunk lanes are exec-masked off (NO
// dummy-bin — same-address LDS atomics serialize ~62-way; R9 lesson).
__global__ __launch_bounds__(256) void hist_kernel(
    const int* __restrict__ src, const int* __restrict__ dst,
    unsigned short* __restrict__ parts, int E, int es) {
  __shared__ unsigned int h[CHUNK];
  const int t = threadIdx.x;
  const int slice = blockIdx.x;
  const int chunk = blockIdx.y;
  const int arr = blockIdx.z;
  for (int i = t; i < CHUNK; i += 256) h[i] = 0;
  __syncthreads();
  const int* __restrict__ idx = arr ? dst : src;
  const int base = chunk * CHUNK;
  const int e0 = slice * es;
  const int e1 = min(e0 + es, E);
  int e = e0 + t;
  for (; e + 768 < e1; e += 1024) {
    int i0 = idx[e], i1 = idx[e + 256], i2 = idx[e + 512], i3 = idx[e + 768];
    unsigned v0 = (unsigned)(i0 - base);
    unsigned v1 = (unsigned)(i1 - base);
    unsigned v2 = (unsigned)(i2 - base);
    unsigned v3 = (unsigned)(i3 - base);
    if (v0 < CHUNK) atomicAdd(&h[v0], 1u);
    if (v1 < CHUNK) atomicAdd(&h[v1], 1u);
    if (v2 < CHUNK) atomicAdd(&h[v2], 1u);
    if (v3 < CHUNK) atomicAdd(&h[v3], 1u);
  }
  for (; e < e1; e += 256) {
    unsigned v = (unsigned)(idx[e] - base);
    if (v < CHUNK) atomicAdd(&h[v], 1u);
  }
  __syncthreads();
  unsigned short* p = parts + (((size_t)arr * gridDim.y + chunk) * SB + slice) * CHUNK;
  for (int i = t; i < CHUNK; i += 256) p[i] = (unsigned short)h[i];
}

// ---- pass 2: register-batched reduce of partials (no atomics) -------------
__global__ __launch_bounds__(256) void reduce_kernel(
    unsigned short* __restrict__ parts,
    int* __restrict__ deg_in, float* __restrict__ nsrc, float* __restrict__ ndst,
    int* __restrict__ sp, int N, int nch) {
  const int t = threadIdx.x;
  const int n = blockIdx.x * 256 + t;
  int sumD = 0;
  if (n < N) {
    const int chunk = n / CHUNK;
    const int local = n % CHUNK;
    const size_t strideA = (size_t)nch * SB * CHUNK;
    const unsigned short* __restrict__ pS = parts + ((size_t)chunk * SB) * CHUNK + local;
    unsigned short* __restrict__ pD = parts + strideA + ((size_t)chunk * SB) * CHUNK + local;
    int sumS = 0;
    #pragma unroll
    for (int s = 0; s < SB; ++s) sumS += (int)pS[(size_t)s * CHUNK];
    unsigned short vD[SB];
    #pragma unroll
    for (int s = 0; s < SB; ++s) vD[s] = pD[(size_t)s * CHUNK];
    #pragma unroll
    for (int s = 0; s < SB; ++s) {
      int c = (int)vD[s];
      vD[s] = (unsigned short)sumD;   // per-slice exclusive offset
      sumD += c;
    }
    #pragma unroll
    for (int s = 0; s < SB; ++s) pD[(size_t)s * CHUNK] = vD[s];
    deg_in[n] = sumD;
    nsrc[n] = 1.0f / sqrtf((float)max(sumS, 1));
    ndst[n] = 1.0f / sqrtf((float)max(sumD, 1));
  }
  int v = sumD;
  #pragma unroll
  for (int d = 32; d > 0; d >>= 1) v += __shfl_xor(v, d);
  __shared__ int ws[4];
  if ((t & 63) == 0) ws[t >> 6] = v;
  __syncthreads();
  if (t == 0) sp[blockIdx.x] = ws[0] + ws[1] + ws[2] + ws[3];
}

// ---- scan of block sums (single block, nb<=256) ---------------------------
__global__ void scan_mid(int* __restrict__ part, int* __restrict__ total_out, int nb) {
  const int tid = threadIdx.x;
  const int lane = tid & 63;
  const int wv = tid >> 6;
  int v = (tid < nb) ? part[tid] : 0;
  int x = v;
  #pragma unroll
  for (int d = 1; d < 64; d <<= 1) {
    int y = __shfl_up(x, d);
    if (lane >= d) x += y;
  }
  __shared__ int ws[4];
  if (lane == 63) ws[wv] = x;
  __syncthreads();
  int woff = 0;
  for (int k = 0; k < wv; ++k) woff += ws[k];
  if (tid < nb) part[tid] = woff + x - v;
  if (tid == 255) *total_out = woff + x;
}

// ---- block-local exclusive scan + block offset -> rowptr ------------------
__global__ void scan_final(const int* __restrict__ deg, const int* __restrict__ part,
                           int* __restrict__ rowptr, int n) {
  const int tid = threadIdx.x;
  const int i = blockIdx.x * 256 + tid;
  const int lane = tid & 63;
  const int wv = tid >> 6;
  int v = (i < n) ? deg[i] : 0;
  int x = v;
  #pragma unroll
  for (int d = 1; d < 64; d <<= 1) {
    int y = __shfl_up(x, d);
    if (lane >= d) x += y;
  }
  __shared__ int ws[4];
  if (lane == 63) ws[wv] = x;
  __syncthreads();
  int woff = 0;
  for (int k = 0; k < wv; ++k) woff += ws[k];
  if (i < n) rowptr[i] = part[blockIdx.x] + woff + x - v;
}

// ---- pass 3: LDS rank + scatter -> colidx ----------------------------------
// VERBATIM round-4 inner loop (round-sequential: within-row order tracks
// edge order). DO NOT UNROLL (numerics).
__global__ __launch_bounds__(256) void fillrank_kernel(
    const int* __restrict__ src, const int* __restrict__ dst,
    const unsigned short* __restrict__ partD, const int* __restrict__ rowptr,
    int* __restrict__ colidx, int E, int es) {
  __shared__ unsigned int h[CHUNK];
  const int t = threadIdx.x;
  const int slice = blockIdx.x;
  const int chunk = blockIdx.y;
  for (int i = t; i < CHUNK; i += 256) h[i] = 0;
  __syncthreads();
  const int base = chunk * CHUNK;
  const unsigned short* __restrict__ po = partD + ((size_t)chunk * SB + slice) * CHUNK;
  const int e0 = slice * es;
  const int e1 = min(e0 + es, E);
  for (int e = e0 + t; e < e1; e += 256) {
    int d = dst[e];
    unsigned v = (unsigned)(d - base);
    if (v < CHUNK) {
      int rank = (int)atomicAdd(&h[v], 1u);
      int slot = rowptr[d] + (int)po[v] + rank;
      colidx[slot] = src[e];
    }
  }
}

// ---- tiled GEMM: out[n][c] = sum_k (nsrc[n]*A[n][k])*W[k][c], C=128 -------
#define BM 128
#define BKC 32
__global__ __launch_bounds__(256) void gemm_scaled(
    const float* __restrict__ A, const float* __restrict__ W,
    const float* __restrict__ nsrc, float* __restrict__ out,
    int nrows, int K) {
  __shared__ __align__(16) float As[BM][BKC + 4];
  __shared__ __align__(16) float Ws[BKC][DHID];
  const int tid = threadIdx.x;
  const int row0 = blockIdx.x * BM;
  const int cx = tid & 15;
  const int ry = tid >> 4;
  const int lr = tid >> 1;
  const int lk = (tid & 1) * 16;
  const int wk = tid >> 3;
  const int wc = (tid & 7) * 4;

  float4 acc[8][2];
  #pragma unroll
  for (int r = 0; r < 8; ++r) {
    acc[r][0] = make_float4(0.f, 0.f, 0.f, 0.f);
    acc[r][1] = make_float4(0.f, 0.f, 0.f, 0.f);
  }

  const int arow = row0 + lr;
  const float scale = (arow < nrows) ? nsrc[arow] : 0.f;

  for (int k0 = 0; k0 < K; k0 += BKC) {
    if (arow < nrows) {
      const float4* ap = (const float4*)(A + (size_t)arow * K + k0 + lk);
      #pragma unroll
      for (int j = 0; j < 4; ++j) {
        float4 v = ap[j];
        v.x *= scale; v.y *= scale; v.z *= scale; v.w *= scale;
        *(float4*)&As[lr][lk + j * 4] = v;
      }
    } else {
      #pragma unroll
      for (int j = 0; j < 4; ++j)
        *(float4*)&As[lr][lk + j * 4] = make_float4(0.f, 0.f, 0.f, 0.f);
    }
    {
      const float* wp = W + (size_t)(k0 + wk) * DHID;
      #pragma unroll
      for (int j = 0; j < 4; ++j)
        *(float4*)&Ws[wk][wc + j * 32] = *(const float4*)(wp + wc + j * 32);
    }
    __syncthreads();
    #pragma unroll 4
    for (int kk = 0; kk < BKC; kk += 2) {
      float4 w00 = *(float4*)&Ws[kk][cx * 4];
      float4 w01 = *(float4*)&Ws[kk][64 + cx * 4];
      float4 w10 = *(float4*)&Ws[kk + 1][cx * 4];
      float4 w11 = *(float4*)&Ws[kk + 1][64 + cx * 4];
      #pragma unroll
      for (int r = 0; r < 8; ++r) {
        float2 a = *(float2*)&As[ry + 16 * r][kk];
        fma4(acc[r][0], a.x, w00);
        fma4(acc[r][1], a.x, w01);
        fma4(acc[r][0], a.y, w10);
        fma4(acc[r][1], a.y, w11);
      }
    }
    __syncthreads();
  }
  #pragma unroll
  for (int r = 0; r < 8; ++r) {
    int row = row0 + ry + 16 * r;
    if (row < nrows) {
      float* op = out + (size_t)row * DHID;
      *(float4*)(op + cx * 4) = acc[r][0];
      *(float4*)(op + 64 + cx * 4) = acc[r][1];
    }
  }
}

// ---- aggregation: VERBATIM round-4-passing version ------------------------
__global__ void agg_kernel(const float* __restrict__ hB, const int* __restrict__ rowptr,
                           const int* __restrict__ colidx, const float* __restrict__ ndst,
                           const float* __restrict__ bias, float* __restrict__ out, int N) {
  int wid = (blockIdx.x * blockDim.x + threadIdx.x) >> 6;
  int lane = threadIdx.x & 63;
  if (wid >= N) return;
  int beg = rowptr[wid];
  int end = rowptr[wid + 1];
  const int half = lane >> 5;
  const int col = (lane & 31) * 4;
  float4 acc = make_float4(0.f, 0.f, 0.f, 0.f);

  for (int c0 = beg; c0 < end; c0 += 64) {
    int cnt = min(end - c0, 64);
    int myidx = (lane < cnt) ? colidx[c0 + lane] : 0;
    int pairs = cnt >> 1;
    int j = 0;
    for (; j + 4 <= pairs; j += 4) {
      int s0 = __shfl(myidx, 2 * j + half);
      int s1 = __shfl(myidx, 2 * j + 2 + half);
      int s2 = __shfl(myidx, 2 * j + 4 + half);
      int s3 = __shfl(myidx, 2 * j + 6 + half);
      float4 v0 = *(const float4*)(hB + (size_t)s0 * DHID + col);
      float4 v1 = *(const float4*)(hB + (size_t)s1 * DHID + col);
      float4 v2 = *(const float4*)(hB + (size_t)s2 * DHID + col);
      float4 v3 = *(const float4*)(hB + (size_t)s3 * DHID + col);
      add4(acc, v0); add4(acc, v1); add4(acc, v2); add4(acc, v3);
    }
    for (; j < pairs; ++j) {
      int s = __shfl(myidx, 2 * j + half);
      float4 v = *(const float4*)(hB + (size_t)s * DHID + col);
      add4(acc, v);
    }
    if (cnt & 1) {
      int s = __shfl(myidx, cnt - 1);
      if (half == 0) {
        float4 v = *(const float4*)(hB + (size_t)s * DHID + col);
        add4(acc, v);
      }
    }
  }
  acc.x += __shfl_xor(acc.x, 32);
  acc.y += __shfl_xor(acc.y, 32);
  acc.z += __shfl_xor(acc.z, 32);
  acc.w += __shfl_xor(acc.w, 32);
  if (half == 0) {
    float nd = ndst[wid];
    float4 b = *(const float4*)(bias + col);
    float4 o;
    o.x = fmaxf(fmaf(acc.x, nd, b.x), 0.f);
    o.y = fmaxf(fmaf(acc.y, nd, b.y), 0.f);
    o.z = fmaxf(fmaf(acc.z, nd, b.z), 0.f);
    o.w = fmaxf(fmaf(acc.w, nd, b.w), 0.f);
    *(float4*)(out + (size_t)wid * DHID + col) = o;
  }
}

// ---- mean-pool: run-flush over sorted gid, fused per-graph counting -------
__global__ void pool_kernel(const float* __restrict__ h, const int* __restrict__ gid,
                            float* __restrict__ pooled, int* __restrict__ cnt,
                            int N, int C) {
  int wid = (blockIdx.x * blockDim.x + threadIdx.x) >> 6;
  int lane = threadIdx.x & 63;
  int n0 = wid * C;
  if (n0 >= N) return;
  int n1 = min(n0 + C, N);
  int gcur = gid[n0];
  int runcnt = 0;
  float2 acc = make_float2(0.f, 0.f);
  for (int nd = n0; nd < n1; ++nd) {
    int g = gid[nd];
    if (g != gcur) {
      atomicAdd(&pooled[(size_t)gcur * DHID + lane * 2], acc.x);
      atomicAdd(&pooled[(size_t)gcur * DHID + lane * 2 + 1], acc.y);
      if (lane == 0) atomicAdd(&cnt[gcur], runcnt);
      acc = make_float2(0.f, 0.f);
      runcnt = 0;
      gcur = g;
    }
    const float2 v = *(const float2*)(h + (size_t)nd * DHID + lane * 2);
    acc.x += v.x;
    acc.y += v.y;
    ++runcnt;
  }
  atomicAdd(&pooled[(size_t)gcur * DHID + lane * 2], acc.x);
  atomicAdd(&pooled[(size_t)gcur * DHID + lane * 2 + 1], acc.y);
  if (lane == 0) atomicAdd(&cnt[gcur], runcnt);
}

// ---- MLP head: one block (128 thr) per graph ------------------------------
__global__ void mlp_kernel(const float* __restrict__ psu, const float* __restrict__ psv,
                           const int* __restrict__ cnt_su, const int* __restrict__ cnt_sv,
                           const float* __restrict__ gf,
                           const float* __restrict__ W0, const float* __restrict__ b0,
                           const float* __restrict__ W1, const float* __restrict__ b1,
                           const float* __restrict__ W2, const float* __restrict__ b2,
                           float* __restrict__ out) {
  int g = blockIdx.x;
  int t = threadIdx.x;  // 128 threads
  __shared__ float comb[260];
  __shared__ float h0[128];
  __shared__ float h1[64];
  float inv_su = 1.0f / (float)max(cnt_su[g], 1);
  float inv_sv = 1.0f / (float)max(cnt_sv[g], 1);
  comb[t] = psu[(size_t)g * DHID + t] * inv_su;
  comb[128 + t] = psv[(size_t)g * DHID + t] * inv_sv;
  if (t < 4) comb[256 + t] = gf[g * 4 + t];
  __syncthreads();
  float acc = b0[t];
  for (int k = 0; k < 260; ++k) acc = fmaf(comb[k], W0[k * 128 + t], acc);
  h0[t] = fmaxf(acc, 0.f);
  __syncthreads();
  if (t < 64) {
    float a = b1[t];
    for (int k = 0; k < 128; ++k) a = fmaf(h0[k], W1[k * 64 + t], a);
    h1[t] = fmaxf(a, 0.f);
  }
  __syncthreads();
  if (t < 64) {
    float p = h1[t] * W2[t];
    #pragma unroll
    for (int d = 32; d > 0; d >>= 1) p += __shfl_down(p, d);
    if (t == 0) out[g] = p + b2[0];
  }
}

// ---------------------------------------------------------------------------
extern "C" void kernel_launch(void* const* d_in, const int* in_sizes, int n_in,
                              void* d_out, int out_size, void* d_ws, size_t ws_size,
                              hipStream_t stream) {
  const float* solute_x  = (const float*)d_in[0];
  const float* solvent_x = (const float*)d_in[1];
  const float* gfeat     = (const float*)d_in[2];
  const int* su_src = (const int*)d_in[3];
  const int* su_dst = (const int*)d_in[4];
  const int* sv_src = (const int*)d_in[5];
  const int* sv_dst = (const int*)d_in[6];
  const int* su_gid = (const int*)d_in[7];
  const int* sv_gid = (const int*)d_in[8];
  const float* enc_W[2][3] = {
    {(const float*)d_in[9],  (const float*)d_in[10], (const float*)d_in[11]},
    {(const float*)d_in[13], (const float*)d_in[14], (const float*)d_in[15]}};
  const float* enc_b[2] = {(const float*)d_in[12], (const float*)d_in[16]};
  const float* mW0 = (const float*)d_in[17];
  const float* mb0 = (const float*)d_in[18];
  const float* mW1 = (const float*)d_in[19];
  const float* mb1 = (const float*)d_in[20];
  const float* mW2 = (const float*)d_in[21];
  const float* mb2 = (const float*)d_in[22];

  const int N = in_sizes[0] / 64;   // 50000
  const int E = in_sizes[3];        // 800000
  const int G = in_sizes[2] / 4;    // 256

  const int* srcs[2] = {su_src, sv_src};
  const int* dsts[2] = {su_dst, sv_dst};
  const int* gids[2] = {su_gid, sv_gid};
  const float* xs[2] = {solute_x, solvent_x};

  // workspace carve-up (256B aligned)
  char* ws = (char*)d_ws;
  size_t off = 0;
  auto alloc = [&](size_t bytes) -> void* {
    void* p = ws + off;
    off = (off + bytes + 255) & ~(size_t)255;
    return p;
  };
  const int NB = (N + 255) / 256;            // rowptr scan blocks (196)
  const int NCH = (N + CHUNK - 1) / CHUNK;   // chunks (32)
  const int RB = (NCH * CHUNK + 255) / 256;  // reduce blocks (200)
  const int ES = (E + SB - 1) / SB;          // edges per slice (25000)
  const size_t arrStride = (size_t)NCH * SB * CHUNK;  // u16 elems per array

  int*   deg_in  = (int*)alloc((size_t)N * 4);
  float* nsrc    = (float*)alloc((size_t)N * 4);
  float* ndst    = (float*)alloc((size_t)N * 4);
  int*   rowptr  = (int*)alloc((size_t)(N + 1) * 4);
  int*   sp      = (int*)alloc((size_t)RB * 4);
  unsigned short* parts = (unsigned short*)alloc(2 * arrStride * 2);
  int*   colidx  = (int*)alloc((size_t)E * 4);
  float* bufA    = (float*)alloc((size_t)N * DHID * 4);
  float* bufB    = (float*)alloc((size_t)N * DHID * 4);
  float* pbase   = (float*)alloc(((size_t)2 * G * DHID + 2 * G) * 4);
  float* pooled_su = pbase;
  float* pooled_sv = pbase + (size_t)G * DHID;
  int*   cnt_su    = (int*)(pbase + (size_t)2 * G * DHID);
  int*   cnt_sv    = cnt_su + G;
  (void)ws_size; (void)n_in; (void)out_size;

  float* pooleds[2] = {pooled_su, pooled_sv};
  int*   cnts[2]    = {cnt_su, cnt_sv};

  hipMemsetAsync(pbase, 0, ((size_t)2 * G * DHID + 2 * G) * 4, stream);

  const int TB = 256;
  const int ggrid = (N + BM - 1) / BM;
  const int agrid = (N + 3) / 4;               // wave per node
  const int PC = 25;                           // nodes per wave in pool
  const int pwaves = (N + PC - 1) / PC;
  const int pgrid = (pwaves + 3) / 4;

  for (int enc = 0; enc < 2; ++enc) {
    hist_kernel<<<dim3(SB, NCH, 2), TB, 0, stream>>>(srcs[enc], dsts[enc], parts, E, ES);
    reduce_kernel<<<RB, TB, 0, stream>>>(parts, deg_in, nsrc, ndst, sp, N, NCH);
    scan_mid<<<1, 256, 0, stream>>>(sp, rowptr + N, NB);
    scan_final<<<NB, 256, 0, stream>>>(deg_in, sp, rowptr, N);
    fillrank_kernel<<<dim3(SB, NCH), TB, 0, stream>>>(srcs[enc], dsts[enc],
                                                      parts + arrStride, rowptr,
                                                      colidx, E, ES);

    const float* in = xs[enc];
    int K = 64;
    for (int l = 0; l < 3; ++l) {
      gemm_scaled<<<ggrid, TB, 0, stream>>>(in, enc_W[enc][l], nsrc, bufB, N, K);
      agg_kernel<<<agrid, TB, 0, stream>>>(bufB, rowptr, colidx, ndst,
                                           enc_b[enc] + l * DHID, bufA, N);
      in = bufA;
      K = DHID;
    }
    pool_kernel<<<pgrid, TB, 0, stream>>>(bufA, gids[enc], pooleds[enc], cnts[enc], N, PC);
  }

  mlp_kernel<<<G, 128, 0, stream>>>(pooled_su, pooled_sv, cnt_su, cnt_sv, gfeat,
                                    mW0, mb0, mW1, mb1, mW2, mb2, (float*)d_out);
}

// Round 11
// 582.653 us; speedup vs baseline: 1.6581x; 1.1434x over previous
//
#include <hip/hip_runtime.h>

// ---------------------------------------------------------------------------
// DualGNN: 2x (3-layer GCN encoder + mean-pool) + MLP head. All f32.
// NUMERICS POLICY (hard-won, R5-R10): inner FP loops are FROZEN (verbatim
// round-4). SB=32 frozen. fillrank round-sequential, NO unroll. agg verbatim.
// hist guarded atomics (no dummy bin — R9: 62-way same-address serialization).
// R11: batch the two encoders into each launch via a grid dimension — pure
// pointer arithmetic, inner code byte-identical => bit-identical numerics.
// Falls back to sequential (R10-equivalent) if ws_size < batched need.
// ---------------------------------------------------------------------------

#define DHID 128
#define CHUNK 1600    // nodes per chunk (LDS histo: 6.4 KB)
#define SB 32         // edge slices — DO NOT CHANGE (numerics)

static __device__ __forceinline__ void fma4(float4& o, float a, const float4& w) {
  o.x = fmaf(a, w.x, o.x);
  o.y = fmaf(a, w.y, o.y);
  o.z = fmaf(a, w.z, o.z);
  o.w = fmaf(a, w.w, o.w);
}
static __device__ __forceinline__ void add4(float4& o, const float4& v) {
  o.x += v.x; o.y += v.y; o.z += v.z; o.w += v.w;
}

// ---- pass 1: privatized histograms -> u16 partials (enc-batched) ----------
// grid (SB, NCH, 2*NE): z&1 = arr (0:src,1:dst), z>>1 = enc.
__global__ __launch_bounds__(256) void hist_kernel(
    const int* __restrict__ src0, const int* __restrict__ dst0,
    const int* __restrict__ src1, const int* __restrict__ dst1,
    unsigned short* __restrict__ parts, int E, int es, size_t encPS) {
  __shared__ unsigned int h[CHUNK];
  const int t = threadIdx.x;
  const int slice = blockIdx.x;
  const int chunk = blockIdx.y;
  const int arr = blockIdx.z & 1;
  const int enc = blockIdx.z >> 1;
  for (int i = t; i < CHUNK; i += 256) h[i] = 0;
  __syncthreads();
  const int* __restrict__ idx = arr ? (enc ? dst1 : dst0) : (enc ? src1 : src0);
  unsigned short* __restrict__ pe = parts + (size_t)enc * encPS;
  const int base = chunk * CHUNK;
  const int e0 = slice * es;
  const int e1 = min(e0 + es, E);
  int e = e0 + t;
  for (; e + 768 < e1; e += 1024) {
    int i0 = idx[e], i1 = idx[e + 256], i2 = idx[e + 512], i3 = idx[e + 768];
    unsigned v0 = (unsigned)(i0 - base);
    unsigned v1 = (unsigned)(i1 - base);
    unsigned v2 = (unsigned)(i2 - base);
    unsigned v3 = (unsigned)(i3 - base);
    if (v0 < CHUNK) atomicAdd(&h[v0], 1u);
    if (v1 < CHUNK) atomicAdd(&h[v1], 1u);
    if (v2 < CHUNK) atomicAdd(&h[v2], 1u);
    if (v3 < CHUNK) atomicAdd(&h[v3], 1u);
  }
  for (; e < e1; e += 256) {
    unsigned v = (unsigned)(idx[e] - base);
    if (v < CHUNK) atomicAdd(&h[v], 1u);
  }
  __syncthreads();
  unsigned short* p = pe + (((size_t)arr * gridDim.y + chunk) * SB + slice) * CHUNK;
  for (int i = t; i < CHUNK; i += 256) p[i] = (unsigned short)h[i];
}

// ---- pass 2: register-batched reduce (enc-batched via blockIdx.y) ---------
__global__ __launch_bounds__(256) void reduce_kernel(
    unsigned short* __restrict__ parts,
    int* __restrict__ deg_in, float* __restrict__ nsrc, float* __restrict__ ndst,
    int* __restrict__ sp, int N, int nch,
    size_t encPS, size_t sN, size_t sSP) {
  const int enc = blockIdx.y;
  parts += (size_t)enc * encPS;
  deg_in += (size_t)enc * sN;
  nsrc += (size_t)enc * sN;
  ndst += (size_t)enc * sN;
  sp += (size_t)enc * sSP;
  const int t = threadIdx.x;
  const int n = blockIdx.x * 256 + t;
  int sumD = 0;
  if (n < N) {
    const int chunk = n / CHUNK;
    const int local = n % CHUNK;
    const size_t strideA = (size_t)nch * SB * CHUNK;
    const unsigned short* __restrict__ pS = parts + ((size_t)chunk * SB) * CHUNK + local;
    unsigned short* __restrict__ pD = parts + strideA + ((size_t)chunk * SB) * CHUNK + local;
    int sumS = 0;
    #pragma unroll
    for (int s = 0; s < SB; ++s) sumS += (int)pS[(size_t)s * CHUNK];
    unsigned short vD[SB];
    #pragma unroll
    for (int s = 0; s < SB; ++s) vD[s] = pD[(size_t)s * CHUNK];
    #pragma unroll
    for (int s = 0; s < SB; ++s) {
      int c = (int)vD[s];
      vD[s] = (unsigned short)sumD;   // per-slice exclusive offset
      sumD += c;
    }
    #pragma unroll
    for (int s = 0; s < SB; ++s) pD[(size_t)s * CHUNK] = vD[s];
    deg_in[n] = sumD;
    nsrc[n] = 1.0f / sqrtf((float)max(sumS, 1));
    ndst[n] = 1.0f / sqrtf((float)max(sumD, 1));
  }
  int v = sumD;
  #pragma unroll
  for (int d = 32; d > 0; d >>= 1) v += __shfl_xor(v, d);
  __shared__ int ws[4];
  if ((t & 63) == 0) ws[t >> 6] = v;
  __syncthreads();
  if (t == 0) sp[blockIdx.x] = ws[0] + ws[1] + ws[2] + ws[3];
}

// ---- scan of block sums (one block per enc) -------------------------------
__global__ void scan_mid(int* __restrict__ sp, int* __restrict__ rowptr,
                         int nb, int N, size_t sSP, size_t sRP) {
  const int enc = blockIdx.x;
  int* part = sp + (size_t)enc * sSP;
  int* total_out = rowptr + (size_t)enc * sRP + N;
  const int tid = threadIdx.x;
  const int lane = tid & 63;
  const int wv = tid >> 6;
  int v = (tid < nb) ? part[tid] : 0;
  int x = v;
  #pragma unroll
  for (int d = 1; d < 64; d <<= 1) {
    int y = __shfl_up(x, d);
    if (lane >= d) x += y;
  }
  __shared__ int ws[4];
  if (lane == 63) ws[wv] = x;
  __syncthreads();
  int woff = 0;
  for (int k = 0; k < wv; ++k) woff += ws[k];
  if (tid < nb) part[tid] = woff + x - v;
  if (tid == 255) *total_out = woff + x;
}

// ---- block-local exclusive scan + block offset -> rowptr (enc-batched) ----
__global__ void scan_final(const int* __restrict__ deg, const int* __restrict__ sp,
                           int* __restrict__ rowptr, int n,
                           size_t sN, size_t sSP, size_t sRP) {
  const int enc = blockIdx.y;
  deg += (size_t)enc * sN;
  const int* part = sp + (size_t)enc * sSP;
  rowptr += (size_t)enc * sRP;
  const int tid = threadIdx.x;
  const int i = blockIdx.x * 256 + tid;
  const int lane = tid & 63;
  const int wv = tid >> 6;
  int v = (i < n) ? deg[i] : 0;
  int x = v;
  #pragma unroll
  for (int d = 1; d < 64; d <<= 1) {
    int y = __shfl_up(x, d);
    if (lane >= d) x += y;
  }
  __shared__ int ws[4];
  if (lane == 63) ws[wv] = x;
  __syncthreads();
  int woff = 0;
  for (int k = 0; k < wv; ++k) woff += ws[k];
  if (i < n) rowptr[i] = part[blockIdx.y == enc ? blockIdx.x : blockIdx.x] + woff + x - v;
}

// ---- pass 3: LDS rank + scatter -> colidx (enc-batched) -------------------
// VERBATIM round-4 inner loop. DO NOT UNROLL (numerics).
__global__ __launch_bounds__(256) void fillrank_kernel(
    const int* __restrict__ src0, const int* __restrict__ dst0,
    const int* __restrict__ src1, const int* __restrict__ dst1,
    const unsigned short* __restrict__ parts, const int* __restrict__ rowptr,
    int* __restrict__ colidx, int E, int es,
    size_t encPS, size_t arrStride, size_t sRP, size_t sE) {
  __shared__ unsigned int h[CHUNK];
  const int t = threadIdx.x;
  const int slice = blockIdx.x;
  const int chunk = blockIdx.y;
  const int enc = blockIdx.z;
  for (int i = t; i < CHUNK; i += 256) h[i] = 0;
  __syncthreads();
  const int* __restrict__ src = enc ? src1 : src0;
  const int* __restrict__ dst = enc ? dst1 : dst0;
  const unsigned short* __restrict__ partD = parts + (size_t)enc * encPS + arrStride;
  rowptr += (size_t)enc * sRP;
  colidx += (size_t)enc * sE;
  const int base = chunk * CHUNK;
  const unsigned short* __restrict__ po = partD + ((size_t)chunk * SB + slice) * CHUNK;
  const int e0 = slice * es;
  const int e1 = min(e0 + es, E);
  for (int e = e0 + t; e < e1; e += 256) {
    int d = dst[e];
    unsigned v = (unsigned)(d - base);
    if (v < CHUNK) {
      int rank = (int)atomicAdd(&h[v], 1u);
      int slot = rowptr[d] + (int)po[v] + rank;
      colidx[slot] = src[e];
    }
  }
}

// ---- tiled GEMM (enc-batched via blockIdx.y): FP loop verbatim R4 ---------
#define BM 128
#define BKC 32
__global__ __launch_bounds__(256) void gemm_scaled(
    const float* __restrict__ A0, const float* __restrict__ A1,
    const float* __restrict__ W0p, const float* __restrict__ W1p,
    const float* __restrict__ nsrc, float* __restrict__ out,
    int nrows, int K, size_t sN, size_t sNH) {
  const int enc = blockIdx.y;
  const float* __restrict__ A = enc ? A1 : A0;
  const float* __restrict__ W = enc ? W1p : W0p;
  nsrc += (size_t)enc * sN;
  out += (size_t)enc * sNH;
  __shared__ __align__(16) float As[BM][BKC + 4];
  __shared__ __align__(16) float Ws[BKC][DHID];
  const int tid = threadIdx.x;
  const int row0 = blockIdx.x * BM;
  const int cx = tid & 15;
  const int ry = tid >> 4;
  const int lr = tid >> 1;
  const int lk = (tid & 1) * 16;
  const int wk = tid >> 3;
  const int wc = (tid & 7) * 4;

  float4 acc[8][2];
  #pragma unroll
  for (int r = 0; r < 8; ++r) {
    acc[r][0] = make_float4(0.f, 0.f, 0.f, 0.f);
    acc[r][1] = make_float4(0.f, 0.f, 0.f, 0.f);
  }

  const int arow = row0 + lr;
  const float scale = (arow < nrows) ? nsrc[arow] : 0.f;

  for (int k0 = 0; k0 < K; k0 += BKC) {
    if (arow < nrows) {
      const float4* ap = (const float4*)(A + (size_t)arow * K + k0 + lk);
      #pragma unroll
      for (int j = 0; j < 4; ++j) {
        float4 v = ap[j];
        v.x *= scale; v.y *= scale; v.z *= scale; v.w *= scale;
        *(float4*)&As[lr][lk + j * 4] = v;
      }
    } else {
      #pragma unroll
      for (int j = 0; j < 4; ++j)
        *(float4*)&As[lr][lk + j * 4] = make_float4(0.f, 0.f, 0.f, 0.f);
    }
    {
      const float* wp = W + (size_t)(k0 + wk) * DHID;
      #pragma unroll
      for (int j = 0; j < 4; ++j)
        *(float4*)&Ws[wk][wc + j * 32] = *(const float4*)(wp + wc + j * 32);
    }
    __syncthreads();
    #pragma unroll 4
    for (int kk = 0; kk < BKC; kk += 2) {
      float4 w00 = *(float4*)&Ws[kk][cx * 4];
      float4 w01 = *(float4*)&Ws[kk][64 + cx * 4];
      float4 w10 = *(float4*)&Ws[kk + 1][cx * 4];
      float4 w11 = *(float4*)&Ws[kk + 1][64 + cx * 4];
      #pragma unroll
      for (int r = 0; r < 8; ++r) {
        float2 a = *(float2*)&As[ry + 16 * r][kk];
        fma4(acc[r][0], a.x, w00);
        fma4(acc[r][1], a.x, w01);
        fma4(acc[r][0], a.y, w10);
        fma4(acc[r][1], a.y, w11);
      }
    }
    __syncthreads();
  }
  #pragma unroll
  for (int r = 0; r < 8; ++r) {
    int row = row0 + ry + 16 * r;
    if (row < nrows) {
      float* op = out + (size_t)row * DHID;
      *(float4*)(op + cx * 4) = acc[r][0];
      *(float4*)(op + 64 + cx * 4) = acc[r][1];
    }
  }
}

// ---- aggregation (enc-batched via blockIdx.y): FP loop VERBATIM R4 --------
__global__ void agg_kernel(const float* __restrict__ hB, const int* __restrict__ rowptr,
                           const int* __restrict__ colidx, const float* __restrict__ ndst,
                           const float* __restrict__ bias0, const float* __restrict__ bias1,
                           float* __restrict__ out, int N,
                           size_t sNH, size_t sRP, size_t sE, size_t sN) {
  const int enc = blockIdx.y;
  hB += (size_t)enc * sNH;
  rowptr += (size_t)enc * sRP;
  colidx += (size_t)enc * sE;
  ndst += (size_t)enc * sN;
  out += (size_t)enc * sNH;
  const float* __restrict__ bias = enc ? bias1 : bias0;
  int wid = (blockIdx.x * blockDim.x + threadIdx.x) >> 6;
  int lane = threadIdx.x & 63;
  if (wid >= N) return;
  int beg = rowptr[wid];
  int end = rowptr[wid + 1];
  const int half = lane >> 5;
  const int col = (lane & 31) * 4;
  float4 acc = make_float4(0.f, 0.f, 0.f, 0.f);

  for (int c0 = beg; c0 < end; c0 += 64) {
    int cnt = min(end - c0, 64);
    int myidx = (lane < cnt) ? colidx[c0 + lane] : 0;
    int pairs = cnt >> 1;
    int j = 0;
    for (; j + 4 <= pairs; j += 4) {
      int s0 = __shfl(myidx, 2 * j + half);
      int s1 = __shfl(myidx, 2 * j + 2 + half);
      int s2 = __shfl(myidx, 2 * j + 4 + half);
      int s3 = __shfl(myidx, 2 * j + 6 + half);
      float4 v0 = *(const float4*)(hB + (size_t)s0 * DHID + col);
      float4 v1 = *(const float4*)(hB + (size_t)s1 * DHID + col);
      float4 v2 = *(const float4*)(hB + (size_t)s2 * DHID + col);
      float4 v3 = *(const float4*)(hB + (size_t)s3 * DHID + col);
      add4(acc, v0); add4(acc, v1); add4(acc, v2); add4(acc, v3);
    }
    for (; j < pairs; ++j) {
      int s = __shfl(myidx, 2 * j + half);
      float4 v = *(const float4*)(hB + (size_t)s * DHID + col);
      add4(acc, v);
    }
    if (cnt & 1) {
      int s = __shfl(myidx, cnt - 1);
      if (half == 0) {
        float4 v = *(const float4*)(hB + (size_t)s * DHID + col);
        add4(acc, v);
      }
    }
  }
  acc.x += __shfl_xor(acc.x, 32);
  acc.y += __shfl_xor(acc.y, 32);
  acc.z += __shfl_xor(acc.z, 32);
  acc.w += __shfl_xor(acc.w, 32);
  if (half == 0) {
    float nd = ndst[wid];
    float4 b = *(const float4*)(bias + col);
    float4 o;
    o.x = fmaxf(fmaf(acc.x, nd, b.x), 0.f);
    o.y = fmaxf(fmaf(acc.y, nd, b.y), 0.f);
    o.z = fmaxf(fmaf(acc.z, nd, b.z), 0.f);
    o.w = fmaxf(fmaf(acc.w, nd, b.w), 0.f);
    *(float4*)(out + (size_t)wid * DHID + col) = o;
  }
}

// ---- mean-pool (enc-batched): run-flush over sorted gid -------------------
__global__ void pool_kernel(const float* __restrict__ h,
                            const int* __restrict__ gid0, const int* __restrict__ gid1,
                            float* __restrict__ pooled, int* __restrict__ cnt,
                            int N, int C, int G,
                            size_t sNH) {
  const int enc = blockIdx.y;
  h += (size_t)enc * sNH;
  const int* __restrict__ gid = enc ? gid1 : gid0;
  pooled += (size_t)enc * G * DHID;
  cnt += (size_t)enc * G;
  int wid = (blockIdx.x * blockDim.x + threadIdx.x) >> 6;
  int lane = threadIdx.x & 63;
  int n0 = wid * C;
  if (n0 >= N) return;
  int n1 = min(n0 + C, N);
  int gcur = gid[n0];
  int runcnt = 0;
  float2 acc = make_float2(0.f, 0.f);
  for (int nd = n0; nd < n1; ++nd) {
    int g = gid[nd];
    if (g != gcur) {
      atomicAdd(&pooled[(size_t)gcur * DHID + lane * 2], acc.x);
      atomicAdd(&pooled[(size_t)gcur * DHID + lane * 2 + 1], acc.y);
      if (lane == 0) atomicAdd(&cnt[gcur], runcnt);
      acc = make_float2(0.f, 0.f);
      runcnt = 0;
      gcur = g;
    }
    const float2 v = *(const float2*)(h + (size_t)nd * DHID + lane * 2);
    acc.x += v.x;
    acc.y += v.y;
    ++runcnt;
  }
  atomicAdd(&pooled[(size_t)gcur * DHID + lane * 2], acc.x);
  atomicAdd(&pooled[(size_t)gcur * DHID + lane * 2 + 1], acc.y);
  if (lane == 0) atomicAdd(&cnt[gcur], runcnt);
}

// ---- MLP head: one block (128 thr) per graph ------------------------------
__global__ void mlp_kernel(const float* __restrict__ psu, const float* __restrict__ psv,
                           const int* __restrict__ cnt_su, const int* __restrict__ cnt_sv,
                           const float* __restrict__ gf,
                           const float* __restrict__ W0, const float* __restrict__ b0,
                           const float* __restrict__ W1, const float* __restrict__ b1,
                           const float* __restrict__ W2, const float* __restrict__ b2,
                           float* __restrict__ out) {
  int g = blockIdx.x;
  int t = threadIdx.x;  // 128 threads
  __shared__ float comb[260];
  __shared__ float h0[128];
  __shared__ float h1[64];
  float inv_su = 1.0f / (float)max(cnt_su[g], 1);
  float inv_sv = 1.0f / (float)max(cnt_sv[g], 1);
  comb[t] = psu[(size_t)g * DHID + t] * inv_su;
  comb[128 + t] = psv[(size_t)g * DHID + t] * inv_sv;
  if (t < 4) comb[256 + t] = gf[g * 4 + t];
  __syncthreads();
  float acc = b0[t];
  for (int k = 0; k < 260; ++k) acc = fmaf(comb[k], W0[k * 128 + t], acc);
  h0[t] = fmaxf(acc, 0.f);
  __syncthreads();
  if (t < 64) {
    float a = b1[t];
    for (int k = 0; k < 128; ++k) a = fmaf(h0[k], W1[k * 64 + t], a);
    h1[t] = fmaxf(a, 0.f);
  }
  __syncthreads();
  if (t < 64) {
    float p = h1[t] * W2[t];
    #pragma unroll
    for (int d = 32; d > 0; d >>= 1) p += __shfl_down(p, d);
    if (t == 0) out[g] = p + b2[0];
  }
}

// ---------------------------------------------------------------------------
extern "C" void kernel_launch(void* const* d_in, const int* in_sizes, int n_in,
                              void* d_out, int out_size, void* d_ws, size_t ws_size,
                              hipStream_t stream) {
  const float* solute_x  = (const float*)d_in[0];
  const float* solvent_x = (const float*)d_in[1];
  const float* gfeat     = (const float*)d_in[2];
  const int* su_src = (const int*)d_in[3];
  const int* su_dst = (const int*)d_in[4];
  const int* sv_src = (const int*)d_in[5];
  const int* sv_dst = (const int*)d_in[6];
  const int* su_gid = (const int*)d_in[7];
  const int* sv_gid = (const int*)d_in[8];
  const float* enc_W[2][3] = {
    {(const float*)d_in[9],  (const float*)d_in[10], (const float*)d_in[11]},
    {(const float*)d_in[13], (const float*)d_in[14], (const float*)d_in[15]}};
  const float* enc_b[2] = {(const float*)d_in[12], (const float*)d_in[16]};
  const float* mW0 = (const float*)d_in[17];
  const float* mb0 = (const float*)d_in[18];
  const float* mW1 = (const float*)d_in[19];
  const float* mb1 = (const float*)d_in[20];
  const float* mW2 = (const float*)d_in[21];
  const float* mb2 = (const float*)d_in[22];

  const int N = in_sizes[0] / 64;   // 50000
  const int E = in_sizes[3];        // 800000
  const int G = in_sizes[2] / 4;    // 256

  const int* srcs[2] = {su_src, sv_src};
  const int* dsts[2] = {su_dst, sv_dst};
  const int* gids[2] = {su_gid, sv_gid};
  const float* xs[2] = {solute_x, solvent_x};

  const int NB = (N + 255) / 256;
  const int NCH = (N + CHUNK - 1) / CHUNK;       // 32
  const int RB = (NCH * CHUNK + 255) / 256;      // 200
  const int ES = (E + SB - 1) / SB;              // 25000
  const size_t arrStride = (size_t)NCH * SB * CHUNK;   // u16 elems per array
  const size_t encPS = 2 * arrStride;                  // u16 elems per enc

  // ---- workspace carve (NE = 2 batched if it fits, else NE = 1) ----------
  char* ws = (char*)d_ws;
  int*   deg_in; float* nsrc; float* ndst; int* rowptr; int* sp;
  int*   colidx; float* bufA; unsigned short* parts; float* bufB;
  float* pbase;
  size_t total = 0;
  int NE = 2;
  auto carve = [&](int ne) -> size_t {
    size_t off = 0;
    auto alloc = [&](size_t bytes) -> void* {
      void* p = ws + off;
      off = (off + bytes + 255) & ~(size_t)255;
      return p;
    };
    deg_in = (int*)alloc((size_t)ne * N * 4);
    nsrc   = (float*)alloc((size_t)ne * N * 4);
    ndst   = (float*)alloc((size_t)ne * N * 4);
    rowptr = (int*)alloc((size_t)ne * (N + 1) * 4);
    sp     = (int*)alloc((size_t)ne * RB * 4);
    colidx = (int*)alloc((size_t)ne * E * 4);
    bufA   = (float*)alloc((size_t)ne * N * DHID * 4);
    size_t partsB = (size_t)ne * encPS * 2;
    size_t bufBB  = (size_t)ne * N * DHID * 4;
    char* uni = (char*)alloc(partsB > bufBB ? partsB : bufBB);  // parts dead after fillrank
    parts = (unsigned short*)uni;
    bufB  = (float*)uni;
    pbase = (float*)alloc(((size_t)2 * G * DHID + 2 * G) * 4);
    return off;
  };
  total = carve(2);
  if (total > ws_size) { NE = 1; total = carve(1); }
  (void)n_in; (void)out_size;

  float* pooled_su = pbase;
  float* pooled_sv = pbase + (size_t)G * DHID;
  int*   cnt_su    = (int*)(pbase + (size_t)2 * G * DHID);
  int*   cnt_sv    = cnt_su + G;

  hipMemsetAsync(pbase, 0, ((size_t)2 * G * DHID + 2 * G) * 4, stream);

  const int TB = 256;
  const int ggrid = (N + BM - 1) / BM;
  const int agrid = (N + 3) / 4;
  const int PC = 25;
  const int pwaves = (N + PC - 1) / PC;
  const int pgrid = (pwaves + 3) / 4;

  if (NE == 2) {
    // strides (element units)
    const size_t sN = N, sRP = N + 1, sSP = RB, sE = E, sNH = (size_t)N * DHID;
    hist_kernel<<<dim3(SB, NCH, 4), TB, 0, stream>>>(
        su_src, su_dst, sv_src, sv_dst, parts, E, ES, encPS);
    reduce_kernel<<<dim3(RB, 2), TB, 0, stream>>>(
        parts, deg_in, nsrc, ndst, sp, N, NCH, encPS, sN, sSP);
    scan_mid<<<2, 256, 0, stream>>>(sp, rowptr, NB, N, sSP, sRP);
    scan_final<<<dim3(NB, 2), 256, 0, stream>>>(deg_in, sp, rowptr, N, sN, sSP, sRP);
    fillrank_kernel<<<dim3(SB, NCH, 2), TB, 0, stream>>>(
        su_src, su_dst, sv_src, sv_dst, parts, rowptr, colidx, E, ES,
        encPS, arrStride, sRP, sE);

    const float* A0 = xs[0];
    const float* A1 = xs[1];
    int K = 64;
    for (int l = 0; l < 3; ++l) {
      gemm_scaled<<<dim3(ggrid, 2), TB, 0, stream>>>(
          A0, A1, enc_W[0][l], enc_W[1][l], nsrc, bufB, N, K, sN, sNH);
      agg_kernel<<<dim3(agrid, 2), TB, 0, stream>>>(
          bufB, rowptr, colidx, ndst, enc_b[0] + l * DHID, enc_b[1] + l * DHID,
          bufA, N, sNH, sRP, sE, sN);
      A0 = bufA;
      A1 = bufA + sNH;
      K = DHID;
    }
    pool_kernel<<<dim3(pgrid, 2), TB, 0, stream>>>(
        bufA, su_gid, sv_gid, pooled_su, cnt_su, N, PC, G, sNH);
  } else {
    // sequential fallback (R10-equivalent): NE=1 buffers, loop encoders
    float* pooleds[2] = {pooled_su, pooled_sv};
    int*   cnts[2]    = {cnt_su, cnt_sv};
    for (int enc = 0; enc < 2; ++enc) {
      hist_kernel<<<dim3(SB, NCH, 2), TB, 0, stream>>>(
          srcs[enc], dsts[enc], srcs[enc], dsts[enc], parts, E, ES, 0);
      reduce_kernel<<<dim3(RB, 1), TB, 0, stream>>>(
          parts, deg_in, nsrc, ndst, sp, N, NCH, 0, 0, 0);
      scan_mid<<<1, 256, 0, stream>>>(sp, rowptr, NB, N, 0, 0);
      scan_final<<<dim3(NB, 1), 256, 0, stream>>>(deg_in, sp, rowptr, N, 0, 0, 0);
      fillrank_kernel<<<dim3(SB, NCH, 1), TB, 0, stream>>>(
          srcs[enc], dsts[enc], srcs[enc], dsts[enc], parts, rowptr, colidx,
          E, ES, 0, arrStride, 0, 0);

      const float* in = xs[enc];
      int K = 64;
      for (int l = 0; l < 3; ++l) {
        gemm_scaled<<<dim3(ggrid, 1), TB, 0, stream>>>(
            in, in, enc_W[enc][l], enc_W[enc][l], nsrc, bufB, N, K, 0, 0);
        agg_kernel<<<dim3(agrid, 1), TB, 0, stream>>>(
            bufB, rowptr, colidx, ndst, enc_b[enc] + l * DHID, enc_b[enc] + l * DHID,
            bufA, N, 0, 0, 0, 0);
        in = bufA;
        K = DHID;
      }
      pool_kernel<<<dim3(pgrid, 1), TB, 0, stream>>>(
          bufA, gids[enc], gids[enc], pooleds[enc], cnts[enc], N, PC, G, 0);
    }
  }

  mlp_kernel<<<G, 128, 0, stream>>>(pooled_su, pooled_sv, cnt_su, cnt_sv, gfeat,
                                    mW0, mb0, mW1, mb1, mW2, mb2, (float*)d_out);
}

// Round 12
// 572.541 us; speedup vs baseline: 1.6874x; 1.0177x over previous
//
#include <hip/hip_runtime.h>

// ---------------------------------------------------------------------------
// DualGNN: 2x (3-layer GCN encoder + mean-pool) + MLP head. All f32.
// NUMERICS POLICY (hard-won, R5-R10): inner FP loops are FROZEN (verbatim
// round-4). SB=32 frozen. fillrank round-sequential, NO unroll. agg verbatim.
// hist guarded atomics (no dummy bin — R9: 62-way same-address serialization).
// R11: encoders batched per launch via grid dim (bit-identical numerics).
// R12: CHUNK 1600 -> 3200 (NCH 32 -> 16). Halves the NCH-redundant edge
// re-reads in hist/fillrank (410 -> 205 MB per kernel) while keeping the
// R10-proven occupancy (hist 8 blocks/CU, fillrank 4/CU batched).
// Chunking is by dst VALUE -> order-neutral (R8/R10-validated).
// ---------------------------------------------------------------------------

#define DHID 128
#define CHUNK 3200    // nodes per chunk (LDS histo: 12.8 KB)
#define SB 32         // edge slices — DO NOT CHANGE (numerics)

static __device__ __forceinline__ void fma4(float4& o, float a, const float4& w) {
  o.x = fmaf(a, w.x, o.x);
  o.y = fmaf(a, w.y, o.y);
  o.z = fmaf(a, w.z, o.z);
  o.w = fmaf(a, w.w, o.w);
}
static __device__ __forceinline__ void add4(float4& o, const float4& v) {
  o.x += v.x; o.y += v.y; o.z += v.z; o.w += v.w;
}

// ---- pass 1: privatized histograms -> u16 partials (enc-batched) ----------
// grid (SB, NCH, 2*NE): z&1 = arr (0:src,1:dst), z>>1 = enc.
__global__ __launch_bounds__(256) void hist_kernel(
    const int* __restrict__ src0, const int* __restrict__ dst0,
    const int* __restrict__ src1, const int* __restrict__ dst1,
    unsigned short* __restrict__ parts, int E, int es, size_t encPS) {
  __shared__ unsigned int h[CHUNK];
  const int t = threadIdx.x;
  const int slice = blockIdx.x;
  const int chunk = blockIdx.y;
  const int arr = blockIdx.z & 1;
  const int enc = blockIdx.z >> 1;
  for (int i = t; i < CHUNK; i += 256) h[i] = 0;
  __syncthreads();
  const int* __restrict__ idx = arr ? (enc ? dst1 : dst0) : (enc ? src1 : src0);
  unsigned short* __restrict__ pe = parts + (size_t)enc * encPS;
  const int base = chunk * CHUNK;
  const int e0 = slice * es;
  const int e1 = min(e0 + es, E);
  int e = e0 + t;
  for (; e + 768 < e1; e += 1024) {
    int i0 = idx[e], i1 = idx[e + 256], i2 = idx[e + 512], i3 = idx[e + 768];
    unsigned v0 = (unsigned)(i0 - base);
    unsigned v1 = (unsigned)(i1 - base);
    unsigned v2 = (unsigned)(i2 - base);
    unsigned v3 = (unsigned)(i3 - base);
    if (v0 < CHUNK) atomicAdd(&h[v0], 1u);
    if (v1 < CHUNK) atomicAdd(&h[v1], 1u);
    if (v2 < CHUNK) atomicAdd(&h[v2], 1u);
    if (v3 < CHUNK) atomicAdd(&h[v3], 1u);
  }
  for (; e < e1; e += 256) {
    unsigned v = (unsigned)(idx[e] - base);
    if (v < CHUNK) atomicAdd(&h[v], 1u);
  }
  __syncthreads();
  unsigned short* p = pe + (((size_t)arr * gridDim.y + chunk) * SB + slice) * CHUNK;
  for (int i = t; i < CHUNK; i += 256) p[i] = (unsigned short)h[i];
}

// ---- pass 2: register-batched reduce (enc-batched via blockIdx.y) ---------
__global__ __launch_bounds__(256) void reduce_kernel(
    unsigned short* __restrict__ parts,
    int* __restrict__ deg_in, float* __restrict__ nsrc, float* __restrict__ ndst,
    int* __restrict__ sp, int N, int nch,
    size_t encPS, size_t sN, size_t sSP) {
  const int enc = blockIdx.y;
  parts += (size_t)enc * encPS;
  deg_in += (size_t)enc * sN;
  nsrc += (size_t)enc * sN;
  ndst += (size_t)enc * sN;
  sp += (size_t)enc * sSP;
  const int t = threadIdx.x;
  const int n = blockIdx.x * 256 + t;
  int sumD = 0;
  if (n < N) {
    const int chunk = n / CHUNK;
    const int local = n % CHUNK;
    const size_t strideA = (size_t)nch * SB * CHUNK;
    const unsigned short* __restrict__ pS = parts + ((size_t)chunk * SB) * CHUNK + local;
    unsigned short* __restrict__ pD = parts + strideA + ((size_t)chunk * SB) * CHUNK + local;
    int sumS = 0;
    #pragma unroll
    for (int s = 0; s < SB; ++s) sumS += (int)pS[(size_t)s * CHUNK];
    unsigned short vD[SB];
    #pragma unroll
    for (int s = 0; s < SB; ++s) vD[s] = pD[(size_t)s * CHUNK];
    #pragma unroll
    for (int s = 0; s < SB; ++s) {
      int c = (int)vD[s];
      vD[s] = (unsigned short)sumD;   // per-slice exclusive offset
      sumD += c;
    }
    #pragma unroll
    for (int s = 0; s < SB; ++s) pD[(size_t)s * CHUNK] = vD[s];
    deg_in[n] = sumD;
    nsrc[n] = 1.0f / sqrtf((float)max(sumS, 1));
    ndst[n] = 1.0f / sqrtf((float)max(sumD, 1));
  }
  int v = sumD;
  #pragma unroll
  for (int d = 32; d > 0; d >>= 1) v += __shfl_xor(v, d);
  __shared__ int ws[4];
  if ((t & 63) == 0) ws[t >> 6] = v;
  __syncthreads();
  if (t == 0) sp[blockIdx.x] = ws[0] + ws[1] + ws[2] + ws[3];
}

// ---- scan of block sums (one block per enc) -------------------------------
__global__ void scan_mid(int* __restrict__ sp, int* __restrict__ rowptr,
                         int nb, int N, size_t sSP, size_t sRP) {
  const int enc = blockIdx.x;
  int* part = sp + (size_t)enc * sSP;
  int* total_out = rowptr + (size_t)enc * sRP + N;
  const int tid = threadIdx.x;
  const int lane = tid & 63;
  const int wv = tid >> 6;
  int v = (tid < nb) ? part[tid] : 0;
  int x = v;
  #pragma unroll
  for (int d = 1; d < 64; d <<= 1) {
    int y = __shfl_up(x, d);
    if (lane >= d) x += y;
  }
  __shared__ int ws[4];
  if (lane == 63) ws[wv] = x;
  __syncthreads();
  int woff = 0;
  for (int k = 0; k < wv; ++k) woff += ws[k];
  if (tid < nb) part[tid] = woff + x - v;
  if (tid == 255) *total_out = woff + x;
}

// ---- block-local exclusive scan + block offset -> rowptr (enc-batched) ----
__global__ void scan_final(const int* __restrict__ deg, const int* __restrict__ sp,
                           int* __restrict__ rowptr, int n,
                           size_t sN, size_t sSP, size_t sRP) {
  const int enc = blockIdx.y;
  deg += (size_t)enc * sN;
  const int* part = sp + (size_t)enc * sSP;
  rowptr += (size_t)enc * sRP;
  const int tid = threadIdx.x;
  const int i = blockIdx.x * 256 + tid;
  const int lane = tid & 63;
  const int wv = tid >> 6;
  int v = (i < n) ? deg[i] : 0;
  int x = v;
  #pragma unroll
  for (int d = 1; d < 64; d <<= 1) {
    int y = __shfl_up(x, d);
    if (lane >= d) x += y;
  }
  __shared__ int ws[4];
  if (lane == 63) ws[wv] = x;
  __syncthreads();
  int woff = 0;
  for (int k = 0; k < wv; ++k) woff += ws[k];
  if (i < n) rowptr[i] = part[blockIdx.x] + woff + x - v;
}

// ---- pass 3: LDS rank + scatter -> colidx (enc-batched) -------------------
// VERBATIM round-4 inner loop. DO NOT UNROLL (numerics).
__global__ __launch_bounds__(256) void fillrank_kernel(
    const int* __restrict__ src0, const int* __restrict__ dst0,
    const int* __restrict__ src1, const int* __restrict__ dst1,
    const unsigned short* __restrict__ parts, const int* __restrict__ rowptr,
    int* __restrict__ colidx, int E, int es,
    size_t encPS, size_t arrStride, size_t sRP, size_t sE) {
  __shared__ unsigned int h[CHUNK];
  const int t = threadIdx.x;
  const int slice = blockIdx.x;
  const int chunk = blockIdx.y;
  const int enc = blockIdx.z;
  for (int i = t; i < CHUNK; i += 256) h[i] = 0;
  __syncthreads();
  const int* __restrict__ src = enc ? src1 : src0;
  const int* __restrict__ dst = enc ? dst1 : dst0;
  const unsigned short* __restrict__ partD = parts + (size_t)enc * encPS + arrStride;
  rowptr += (size_t)enc * sRP;
  colidx += (size_t)enc * sE;
  const int base = chunk * CHUNK;
  const unsigned short* __restrict__ po = partD + ((size_t)chunk * SB + slice) * CHUNK;
  const int e0 = slice * es;
  const int e1 = min(e0 + es, E);
  for (int e = e0 + t; e < e1; e += 256) {
    int d = dst[e];
    unsigned v = (unsigned)(d - base);
    if (v < CHUNK) {
      int rank = (int)atomicAdd(&h[v], 1u);
      int slot = rowptr[d] + (int)po[v] + rank;
      colidx[slot] = src[e];
    }
  }
}

// ---- tiled GEMM (enc-batched via blockIdx.y): FP loop verbatim R4 ---------
#define BM 128
#define BKC 32
__global__ __launch_bounds__(256) void gemm_scaled(
    const float* __restrict__ A0, const float* __restrict__ A1,
    const float* __restrict__ W0p, const float* __restrict__ W1p,
    const float* __restrict__ nsrc, float* __restrict__ out,
    int nrows, int K, size_t sN, size_t sNH) {
  const int enc = blockIdx.y;
  const float* __restrict__ A = enc ? A1 : A0;
  const float* __restrict__ W = enc ? W1p : W0p;
  nsrc += (size_t)enc * sN;
  out += (size_t)enc * sNH;
  __shared__ __align__(16) float As[BM][BKC + 4];
  __shared__ __align__(16) float Ws[BKC][DHID];
  const int tid = threadIdx.x;
  const int row0 = blockIdx.x * BM;
  const int cx = tid & 15;
  const int ry = tid >> 4;
  const int lr = tid >> 1;
  const int lk = (tid & 1) * 16;
  const int wk = tid >> 3;
  const int wc = (tid & 7) * 4;

  float4 acc[8][2];
  #pragma unroll
  for (int r = 0; r < 8; ++r) {
    acc[r][0] = make_float4(0.f, 0.f, 0.f, 0.f);
    acc[r][1] = make_float4(0.f, 0.f, 0.f, 0.f);
  }

  const int arow = row0 + lr;
  const float scale = (arow < nrows) ? nsrc[arow] : 0.f;

  for (int k0 = 0; k0 < K; k0 += BKC) {
    if (arow < nrows) {
      const float4* ap = (const float4*)(A + (size_t)arow * K + k0 + lk);
      #pragma unroll
      for (int j = 0; j < 4; ++j) {
        float4 v = ap[j];
        v.x *= scale; v.y *= scale; v.z *= scale; v.w *= scale;
        *(float4*)&As[lr][lk + j * 4] = v;
      }
    } else {
      #pragma unroll
      for (int j = 0; j < 4; ++j)
        *(float4*)&As[lr][lk + j * 4] = make_float4(0.f, 0.f, 0.f, 0.f);
    }
    {
      const float* wp = W + (size_t)(k0 + wk) * DHID;
      #pragma unroll
      for (int j = 0; j < 4; ++j)
        *(float4*)&Ws[wk][wc + j * 32] = *(const float4*)(wp + wc + j * 32);
    }
    __syncthreads();
    #pragma unroll 4
    for (int kk = 0; kk < BKC; kk += 2) {
      float4 w00 = *(float4*)&Ws[kk][cx * 4];
      float4 w01 = *(float4*)&Ws[kk][64 + cx * 4];
      float4 w10 = *(float4*)&Ws[kk + 1][cx * 4];
      float4 w11 = *(float4*)&Ws[kk + 1][64 + cx * 4];
      #pragma unroll
      for (int r = 0; r < 8; ++r) {
        float2 a = *(float2*)&As[ry + 16 * r][kk];
        fma4(acc[r][0], a.x, w00);
        fma4(acc[r][1], a.x, w01);
        fma4(acc[r][0], a.y, w10);
        fma4(acc[r][1], a.y, w11);
      }
    }
    __syncthreads();
  }
  #pragma unroll
  for (int r = 0; r < 8; ++r) {
    int row = row0 + ry + 16 * r;
    if (row < nrows) {
      float* op = out + (size_t)row * DHID;
      *(float4*)(op + cx * 4) = acc[r][0];
      *(float4*)(op + 64 + cx * 4) = acc[r][1];
    }
  }
}

// ---- aggregation (enc-batched via blockIdx.y): FP loop VERBATIM R4 --------
__global__ void agg_kernel(const float* __restrict__ hB, const int* __restrict__ rowptr,
                           const int* __restrict__ colidx, const float* __restrict__ ndst,
                           const float* __restrict__ bias0, const float* __restrict__ bias1,
                           float* __restrict__ out, int N,
                           size_t sNH, size_t sRP, size_t sE, size_t sN) {
  const int enc = blockIdx.y;
  hB += (size_t)enc * sNH;
  rowptr += (size_t)enc * sRP;
  colidx += (size_t)enc * sE;
  ndst += (size_t)enc * sN;
  out += (size_t)enc * sNH;
  const float* __restrict__ bias = enc ? bias1 : bias0;
  int wid = (blockIdx.x * blockDim.x + threadIdx.x) >> 6;
  int lane = threadIdx.x & 63;
  if (wid >= N) return;
  int beg = rowptr[wid];
  int end = rowptr[wid + 1];
  const int half = lane >> 5;
  const int col = (lane & 31) * 4;
  float4 acc = make_float4(0.f, 0.f, 0.f, 0.f);

  for (int c0 = beg; c0 < end; c0 += 64) {
    int cnt = min(end - c0, 64);
    int myidx = (lane < cnt) ? colidx[c0 + lane] : 0;
    int pairs = cnt >> 1;
    int j = 0;
    for (; j + 4 <= pairs; j += 4) {
      int s0 = __shfl(myidx, 2 * j + half);
      int s1 = __shfl(myidx, 2 * j + 2 + half);
      int s2 = __shfl(myidx, 2 * j + 4 + half);
      int s3 = __shfl(myidx, 2 * j + 6 + half);
      float4 v0 = *(const float4*)(hB + (size_t)s0 * DHID + col);
      float4 v1 = *(const float4*)(hB + (size_t)s1 * DHID + col);
      float4 v2 = *(const float4*)(hB + (size_t)s2 * DHID + col);
      float4 v3 = *(const float4*)(hB + (size_t)s3 * DHID + col);
      add4(acc, v0); add4(acc, v1); add4(acc, v2); add4(acc, v3);
    }
    for (; j < pairs; ++j) {
      int s = __shfl(myidx, 2 * j + half);
      float4 v = *(const float4*)(hB + (size_t)s * DHID + col);
      add4(acc, v);
    }
    if (cnt & 1) {
      int s = __shfl(myidx, cnt - 1);
      if (half == 0) {
        float4 v = *(const float4*)(hB + (size_t)s * DHID + col);
        add4(acc, v);
      }
    }
  }
  acc.x += __shfl_xor(acc.x, 32);
  acc.y += __shfl_xor(acc.y, 32);
  acc.z += __shfl_xor(acc.z, 32);
  acc.w += __shfl_xor(acc.w, 32);
  if (half == 0) {
    float nd = ndst[wid];
    float4 b = *(const float4*)(bias + col);
    float4 o;
    o.x = fmaxf(fmaf(acc.x, nd, b.x), 0.f);
    o.y = fmaxf(fmaf(acc.y, nd, b.y), 0.f);
    o.z = fmaxf(fmaf(acc.z, nd, b.z), 0.f);
    o.w = fmaxf(fmaf(acc.w, nd, b.w), 0.f);
    *(float4*)(out + (size_t)wid * DHID + col) = o;
  }
}

// ---- mean-pool (enc-batched): run-flush over sorted gid -------------------
__global__ void pool_kernel(const float* __restrict__ h,
                            const int* __restrict__ gid0, const int* __restrict__ gid1,
                            float* __restrict__ pooled, int* __restrict__ cnt,
                            int N, int C, int G,
                            size_t sNH) {
  const int enc = blockIdx.y;
  h += (size_t)enc * sNH;
  const int* __restrict__ gid = enc ? gid1 : gid0;
  pooled += (size_t)enc * G * DHID;
  cnt += (size_t)enc * G;
  int wid = (blockIdx.x * blockDim.x + threadIdx.x) >> 6;
  int lane = threadIdx.x & 63;
  int n0 = wid * C;
  if (n0 >= N) return;
  int n1 = min(n0 + C, N);
  int gcur = gid[n0];
  int runcnt = 0;
  float2 acc = make_float2(0.f, 0.f);
  for (int nd = n0; nd < n1; ++nd) {
    int g = gid[nd];
    if (g != gcur) {
      atomicAdd(&pooled[(size_t)gcur * DHID + lane * 2], acc.x);
      atomicAdd(&pooled[(size_t)gcur * DHID + lane * 2 + 1], acc.y);
      if (lane == 0) atomicAdd(&cnt[gcur], runcnt);
      acc = make_float2(0.f, 0.f);
      runcnt = 0;
      gcur = g;
    }
    const float2 v = *(const float2*)(h + (size_t)nd * DHID + lane * 2);
    acc.x += v.x;
    acc.y += v.y;
    ++runcnt;
  }
  atomicAdd(&pooled[(size_t)gcur * DHID + lane * 2], acc.x);
  atomicAdd(&pooled[(size_t)gcur * DHID + lane * 2 + 1], acc.y);
  if (lane == 0) atomicAdd(&cnt[gcur], runcnt);
}

// ---- MLP head: one block (128 thr) per graph ------------------------------
__global__ void mlp_kernel(const float* __restrict__ psu, const float* __restrict__ psv,
                           const int* __restrict__ cnt_su, const int* __restrict__ cnt_sv,
                           const float* __restrict__ gf,
                           const float* __restrict__ W0, const float* __restrict__ b0,
                           const float* __restrict__ W1, const float* __restrict__ b1,
                           const float* __restrict__ W2, const float* __restrict__ b2,
                           float* __restrict__ out) {
  int g = blockIdx.x;
  int t = threadIdx.x;  // 128 threads
  __shared__ float comb[260];
  __shared__ float h0[128];
  __shared__ float h1[64];
  float inv_su = 1.0f / (float)max(cnt_su[g], 1);
  float inv_sv = 1.0f / (float)max(cnt_sv[g], 1);
  comb[t] = psu[(size_t)g * DHID + t] * inv_su;
  comb[128 + t] = psv[(size_t)g * DHID + t] * inv_sv;
  if (t < 4) comb[256 + t] = gf[g * 4 + t];
  __syncthreads();
  float acc = b0[t];
  for (int k = 0; k < 260; ++k) acc = fmaf(comb[k], W0[k * 128 + t], acc);
  h0[t] = fmaxf(acc, 0.f);
  __syncthreads();
  if (t < 64) {
    float a = b1[t];
    for (int k = 0; k < 128; ++k) a = fmaf(h0[k], W1[k * 64 + t], a);
    h1[t] = fmaxf(a, 0.f);
  }
  __syncthreads();
  if (t < 64) {
    float p = h1[t] * W2[t];
    #pragma unroll
    for (int d = 32; d > 0; d >>= 1) p += __shfl_down(p, d);
    if (t == 0) out[g] = p + b2[0];
  }
}

// ---------------------------------------------------------------------------
extern "C" void kernel_launch(void* const* d_in, const int* in_sizes, int n_in,
                              void* d_out, int out_size, void* d_ws, size_t ws_size,
                              hipStream_t stream) {
  const float* solute_x  = (const float*)d_in[0];
  const float* solvent_x = (const float*)d_in[1];
  const float* gfeat     = (const float*)d_in[2];
  const int* su_src = (const int*)d_in[3];
  const int* su_dst = (const int*)d_in[4];
  const int* sv_src = (const int*)d_in[5];
  const int* sv_dst = (const int*)d_in[6];
  const int* su_gid = (const int*)d_in[7];
  const int* sv_gid = (const int*)d_in[8];
  const float* enc_W[2][3] = {
    {(const float*)d_in[9],  (const float*)d_in[10], (const float*)d_in[11]},
    {(const float*)d_in[13], (const float*)d_in[14], (const float*)d_in[15]}};
  const float* enc_b[2] = {(const float*)d_in[12], (const float*)d_in[16]};
  const float* mW0 = (const float*)d_in[17];
  const float* mb0 = (const float*)d_in[18];
  const float* mW1 = (const float*)d_in[19];
  const float* mb1 = (const float*)d_in[20];
  const float* mW2 = (const float*)d_in[21];
  const float* mb2 = (const float*)d_in[22];

  const int N = in_sizes[0] / 64;   // 50000
  const int E = in_sizes[3];        // 800000
  const int G = in_sizes[2] / 4;    // 256

  const int* srcs[2] = {su_src, sv_src};
  const int* dsts[2] = {su_dst, sv_dst};
  const int* gids[2] = {su_gid, sv_gid};
  const float* xs[2] = {solute_x, solvent_x};

  const int NB = (N + 255) / 256;
  const int NCH = (N + CHUNK - 1) / CHUNK;       // 16
  const int RB = (NCH * CHUNK + 255) / 256;      // 200
  const int ES = (E + SB - 1) / SB;              // 25000
  const size_t arrStride = (size_t)NCH * SB * CHUNK;   // u16 elems per array
  const size_t encPS = 2 * arrStride;                  // u16 elems per enc

  // ---- workspace carve (NE = 2 batched if it fits, else NE = 1) ----------
  char* ws = (char*)d_ws;
  int*   deg_in; float* nsrc; float* ndst; int* rowptr; int* sp;
  int*   colidx; float* bufA; unsigned short* parts; float* bufB;
  float* pbase;
  size_t total = 0;
  int NE = 2;
  auto carve = [&](int ne) -> size_t {
    size_t off = 0;
    auto alloc = [&](size_t bytes) -> void* {
      void* p = ws + off;
      off = (off + bytes + 255) & ~(size_t)255;
      return p;
    };
    deg_in = (int*)alloc((size_t)ne * N * 4);
    nsrc   = (float*)alloc((size_t)ne * N * 4);
    ndst   = (float*)alloc((size_t)ne * N * 4);
    rowptr = (int*)alloc((size_t)ne * (N + 1) * 4);
    sp     = (int*)alloc((size_t)ne * RB * 4);
    colidx = (int*)alloc((size_t)ne * E * 4);
    bufA   = (float*)alloc((size_t)ne * N * DHID * 4);
    size_t partsB = (size_t)ne * encPS * 2;
    size_t bufBB  = (size_t)ne * N * DHID * 4;
    char* uni = (char*)alloc(partsB > bufBB ? partsB : bufBB);  // parts dead after fillrank
    parts = (unsigned short*)uni;
    bufB  = (float*)uni;
    pbase = (float*)alloc(((size_t)2 * G * DHID + 2 * G) * 4);
    return off;
  };
  total = carve(2);
  if (total > ws_size) { NE = 1; total = carve(1); }
  (void)n_in; (void)out_size;

  float* pooled_su = pbase;
  float* pooled_sv = pbase + (size_t)G * DHID;
  int*   cnt_su    = (int*)(pbase + (size_t)2 * G * DHID);
  int*   cnt_sv    = cnt_su + G;

  hipMemsetAsync(pbase, 0, ((size_t)2 * G * DHID + 2 * G) * 4, stream);

  const int TB = 256;
  const int ggrid = (N + BM - 1) / BM;
  const int agrid = (N + 3) / 4;
  const int PC = 25;
  const int pwaves = (N + PC - 1) / PC;
  const int pgrid = (pwaves + 3) / 4;

  if (NE == 2) {
    // strides (element units)
    const size_t sN = N, sRP = N + 1, sSP = RB, sE = E, sNH = (size_t)N * DHID;
    hist_kernel<<<dim3(SB, NCH, 4), TB, 0, stream>>>(
        su_src, su_dst, sv_src, sv_dst, parts, E, ES, encPS);
    reduce_kernel<<<dim3(RB, 2), TB, 0, stream>>>(
        parts, deg_in, nsrc, ndst, sp, N, NCH, encPS, sN, sSP);
    scan_mid<<<2, 256, 0, stream>>>(sp, rowptr, NB, N, sSP, sRP);
    scan_final<<<dim3(NB, 2), 256, 0, stream>>>(deg_in, sp, rowptr, N, sN, sSP, sRP);
    fillrank_kernel<<<dim3(SB, NCH, 2), TB, 0, stream>>>(
        su_src, su_dst, sv_src, sv_dst, parts, rowptr, colidx, E, ES,
        encPS, arrStride, sRP, sE);

    const float* A0 = xs[0];
    const float* A1 = xs[1];
    int K = 64;
    for (int l = 0; l < 3; ++l) {
      gemm_scaled<<<dim3(ggrid, 2), TB, 0, stream>>>(
          A0, A1, enc_W[0][l], enc_W[1][l], nsrc, bufB, N, K, sN, sNH);
      agg_kernel<<<dim3(agrid, 2), TB, 0, stream>>>(
          bufB, rowptr, colidx, ndst, enc_b[0] + l * DHID, enc_b[1] + l * DHID,
          bufA, N, sNH, sRP, sE, sN);
      A0 = bufA;
      A1 = bufA + sNH;
      K = DHID;
    }
    pool_kernel<<<dim3(pgrid, 2), TB, 0, stream>>>(
        bufA, su_gid, sv_gid, pooled_su, cnt_su, N, PC, G, sNH);
  } else {
    // sequential fallback (R10-equivalent): NE=1 buffers, loop encoders
    float* pooleds[2] = {pooled_su, pooled_sv};
    int*   cnts[2]    = {cnt_su, cnt_sv};
    for (int enc = 0; enc < 2; ++enc) {
      hist_kernel<<<dim3(SB, NCH, 2), TB, 0, stream>>>(
          srcs[enc], dsts[enc], srcs[enc], dsts[enc], parts, E, ES, 0);
      reduce_kernel<<<dim3(RB, 1), TB, 0, stream>>>(
          parts, deg_in, nsrc, ndst, sp, N, NCH, 0, 0, 0);
      scan_mid<<<1, 256, 0, stream>>>(sp, rowptr, NB, N, 0, 0);
      scan_final<<<dim3(NB, 1), 256, 0, stream>>>(deg_in, sp, rowptr, N, 0, 0, 0);
      fillrank_kernel<<<dim3(SB, NCH, 1), TB, 0, stream>>>(
          srcs[enc], dsts[enc], srcs[enc], dsts[enc], parts, rowptr, colidx,
          E, ES, 0, arrStride, 0, 0);

      const float* in = xs[enc];
      int K = 64;
      for (int l = 0; l < 3; ++l) {
        gemm_scaled<<<dim3(ggrid, 1), TB, 0, stream>>>(
            in, in, enc_W[enc][l], enc_W[enc][l], nsrc, bufB, N, K, 0, 0);
        agg_kernel<<<dim3(agrid, 1), TB, 0, stream>>>(
            bufB, rowptr, colidx, ndst, enc_b[enc] + l * DHID, enc_b[enc] + l * DHID,
            bufA, N, 0, 0, 0, 0);
        in = bufA;
        K = DHID;
      }
      pool_kernel<<<dim3(pgrid, 1), TB, 0, stream>>>(
          bufA, gids[enc], gids[enc], pooleds[enc], cnts[enc], N, PC, G, 0);
    }
  }

  mlp_kernel<<<G, 128, 0, stream>>>(pooled_su, pooled_sv, cnt_su, cnt_sv, gfeat,
                                    mW0, mb0, mW1, mb1, mW2, mb2, (float*)d_out);
}